// Round 4
// baseline (2344.153 us; speedup 1.0000x reference)
//
#include <hip/hip_runtime.h>
#include <hip/hip_bf16.h>
#include <math.h>

typedef unsigned short u16;

#define BB 2
#define TT 1024
#define CC 2048
#define HH 32
#define BT (BB*TT)

// Inputs/outputs are fp32 (per reference dtypes). Intermediates in ws are
// bf16 (7 regions x NBTC = 56 MiB; ws_size >= that, established round 3).
// fp32 only in registers (GEMM accum, recurrence state, GN stats) and for
// K-split partials overlapping dead bf16 regions. y scratch lives in the
// second output slot (v0 slot) until copy_v0 overwrites it at the end.

__device__ __forceinline__ float bf2f(u16 u) {
  return __uint_as_float(((unsigned int)u) << 16);
}
__device__ __forceinline__ u16 f2bf(float f) {
  unsigned int x = __float_as_uint(f);
  x += 0x7fffu + ((x >> 16) & 1u);
  return (u16)(x >> 16);
}

// ---------------------------------------------------------------- mix kernel
// out[b,t,c] = x + (x_{t-1} - x) * s[c]   (zero pad at t==0), bf16 out
__global__ __launch_bounds__(256)
void mix_k(const float* __restrict__ x, const float* __restrict__ s,
           u16* __restrict__ out) {
  int idx = blockIdx.x * 256 + threadIdx.x;       // over BT*C
  int c = idx & (CC - 1);
  int t = (idx >> 11) & (TT - 1);                 // C = 2^11, T = 2^10
  float xv = x[idx];
  float xp = (t == 0) ? 0.f : x[idx - CC];
  out[idx] = f2bf(xv + (xp - xv) * s[c]);
}

// ---------------------------------------------------------------- GEMM
// C[M,N] = A[M,K](bf16 ws, pitch K) * W[K,N](fp32 input, pitch N), fp32 accum.
// tile 64x64x16, 256 threads, 4x4 per thread. Epilogue templated.
enum { EPI_PART = 0, EPI_BF = 1, EPI_F32 = 2, EPI_BIAS_SP = 3,
       EPI_BIAS_SIG = 4, EPI_VMIX = 5 };

template<int EPI>
__global__ __launch_bounds__(256)
void gemm_k(const u16* __restrict__ A, const float* __restrict__ W,
            float* __restrict__ outF, u16* __restrict__ outB,
            int M, int N, int K, int kchunk, int NP,
            const float* __restrict__ bias, const u16* __restrict__ p1,
            const float* __restrict__ p2)
{
  __shared__ alignas(16) float As[16][68];
  __shared__ alignas(16) float Bs[16][68];
  const int m0 = blockIdx.x * 64;
  const int n0 = blockIdx.y * 64;
  const int kz = blockIdx.z;
  const int k0base = kz * kchunk;
  const int tid = threadIdx.x;
  const int tx = tid & 15, ty = tid >> 4;
  float acc[4][4] = {{0.f}};
  const int a_m = tid >> 2;
  const int a_k = (tid & 3) << 2;
  const int b_k = tid >> 4;
  const int b_n = (tid & 15) << 2;
  const int niters = kchunk >> 4;
  for (int it = 0; it < niters; ++it) {
    const int k0 = k0base + (it << 4);
    float4 av;
    {
      ushort4 u = *(const ushort4*)(A + (size_t)(m0 + a_m) * K + (k0 + a_k));
      av = make_float4(bf2f(u.x), bf2f(u.y), bf2f(u.z), bf2f(u.w));
    }
    float4 bv;
    {
      int gn = n0 + b_n;
      const float* wp = W + (size_t)(k0 + b_k) * N + gn;
      if (gn + 3 < N) {
        bv = *(const float4*)wp;
      } else {
        bv.x = (gn + 0 < N) ? wp[0] : 0.f;
        bv.y = (gn + 1 < N) ? wp[1] : 0.f;
        bv.z = (gn + 2 < N) ? wp[2] : 0.f;
        bv.w = (gn + 3 < N) ? wp[3] : 0.f;
      }
    }
    __syncthreads();
    As[a_k + 0][a_m] = av.x; As[a_k + 1][a_m] = av.y;
    As[a_k + 2][a_m] = av.z; As[a_k + 3][a_m] = av.w;
    Bs[b_k][b_n + 0] = bv.x; Bs[b_k][b_n + 1] = bv.y;
    Bs[b_k][b_n + 2] = bv.z; Bs[b_k][b_n + 3] = bv.w;
    __syncthreads();
    #pragma unroll
    for (int kk = 0; kk < 16; ++kk) {
      float4 a4 = *(const float4*)&As[kk][ty << 2];
      float4 b4 = *(const float4*)&Bs[kk][tx << 2];
      float ar[4] = {a4.x, a4.y, a4.z, a4.w};
      float br[4] = {b4.x, b4.y, b4.z, b4.w};
      #pragma unroll
      for (int i = 0; i < 4; ++i)
        #pragma unroll
        for (int j = 0; j < 4; ++j)
          acc[i][j] = fmaf(ar[i], br[j], acc[i][j]);
    }
  }
  #pragma unroll
  for (int i = 0; i < 4; ++i) {
    int gm = m0 + (ty << 2) + i;
    #pragma unroll
    for (int j = 0; j < 4; ++j) {
      int gn = n0 + (tx << 2) + j;
      if (gn >= N) continue;
      float r = acc[i][j];
      size_t idx = (size_t)gm * N + gn;
      if (EPI == EPI_PART) {
        outF[((size_t)kz * M + gm) * NP + gn] = r;
      } else if (EPI == EPI_BF) {
        outB[idx] = f2bf(r);
      } else if (EPI == EPI_F32) {
        outF[idx] = r;
      } else if (EPI == EPI_BIAS_SP) {
        // -softplus(-(bias + r)) - 0.5, numerically stable
        float u = bias[gn] + r;
        float z = -u;
        float sp = fmaxf(z, 0.f) + log1pf(expf(-fabsf(z)));
        outB[idx] = f2bf(-sp - 0.5f);
      } else if (EPI == EPI_BIAS_SIG) {
        float u = bias[gn] + r;
        outB[idx] = f2bf(1.f / (1.f + expf(-u)));
      } else if (EPI == EPI_VMIX) {
        float u = bias[gn] + r;
        float sg = 1.f / (1.f + expf(-u));
        float v = bf2f(p1[idx]);
        float v0v = p2[idx];
        outB[idx] = f2bf(v + (v0v - v) * sg);
      }
    }
  }
}

// ---------------------------------------------------------------- K-split reduce
__global__ __launch_bounds__(256)
void reduce_k(const float* __restrict__ part, u16* __restrict__ out,
              int M, int D, int NP, int nz, int act)
{
  int idx = blockIdx.x * 256 + threadIdx.x;
  if (idx >= M * D) return;
  int t = idx / D, n = idx - t * D;
  float s = 0.f;
  for (int z = 0; z < nz; ++z) s += part[((size_t)z * M + t) * NP + n];
  if (act == 1) s = tanhf(s);
  else if (act == 2) s = 1.f / (1.f + expf(-s));
  out[idx] = f2bf(s);
}

// ---------------------------------------------------------------- kk prep
// kk = normalize_per_head(k * kk_s); k <- k * (1 + (a-1)*ka_s)
__global__ __launch_bounds__(256)
void kkprep_k(const u16* __restrict__ k_in, const u16* __restrict__ a_in,
              const float* __restrict__ kk_s, const float* __restrict__ ka_s,
              u16* __restrict__ kk_out, u16* __restrict__ k_out)
{
  int tid = threadIdx.x;
  int lane = tid & 63;
  int wv = tid >> 6;
  int hidx = blockIdx.x * 4 + wv;               // 0 .. BT*H-1
  int h = hidx & (HH - 1);
  int c = (h << 6) + lane;
  size_t base = ((size_t)hidx << 6) + lane;
  float k = bf2f(k_in[base]);
  float kk = k * kk_s[c];
  float ss = kk * kk;
  for (int off = 32; off; off >>= 1) ss += __shfl_xor(ss, off, 64);
  float denom = fmaxf(sqrtf(ss), 1e-12f);
  kk_out[base] = f2bf(kk / denom);
  float a = bf2f(a_in[base]);
  k_out[base] = f2bf(k * (1.f + (a - 1.f) * ka_s[c]));
}

// ---------------------------------------------------------------- RWKV7 recurrence
// one block per (b,h); thread i owns state row i (64 fp32 in registers)
__global__ __launch_bounds__(64)
void rec_k(const u16* __restrict__ r, const u16* __restrict__ w,
           const u16* __restrict__ k, const u16* __restrict__ v,
           const u16* __restrict__ kk, const u16* __restrict__ a,
           u16* __restrict__ y)
{
  const int bh = blockIdx.x;
  const int b = bh >> 5, h = bh & (HH - 1);
  const int lane = threadIdx.x;
  __shared__ alignas(16) float lw[2][64];
  __shared__ alignas(16) float lk[2][64];
  __shared__ alignas(16) float lao[2][64];
  __shared__ alignas(16) float lbo[2][64];
  __shared__ alignas(16) float lr[2][64];
  float st[64];
  #pragma unroll
  for (int j = 0; j < 64; ++j) st[j] = 0.f;
  size_t base = ((size_t)b * TT) * CC + (h << 6) + lane;
  {
    float pw = bf2f(w[base]), pk = bf2f(k[base]), pkk = bf2f(kk[base]),
          pa = bf2f(a[base]), pr = bf2f(r[base]);
    lw[0][lane]  = expf(-expf(pw));
    lk[0][lane]  = pk;
    lao[0][lane] = -pkk;
    lbo[0][lane] = pkk * pa;
    lr[0][lane]  = pr;
  }
  float vi = bf2f(v[base]);
  for (int t = 0; t < TT; ++t) {
    const int buf = t & 1;
    float nw = 0.f, nk = 0.f, nkk = 0.f, na = 0.f, nr = 0.f, nv = 0.f;
    if (t + 1 < TT) {
      size_t bn = base + (size_t)(t + 1) * CC;
      nw = bf2f(w[bn]); nk = bf2f(k[bn]); nkk = bf2f(kk[bn]);
      na = bf2f(a[bn]); nr = bf2f(r[bn]); nv = bf2f(v[bn]);
    }
    __syncthreads();                      // lds[buf] ready
    float sa = 0.f;
    #pragma unroll
    for (int q = 0; q < 16; ++q) {
      float4 a4 = *(const float4*)&lao[buf][q << 2];
      int j = q << 2;
      sa = fmaf(st[j + 0], a4.x, sa);
      sa = fmaf(st[j + 1], a4.y, sa);
      sa = fmaf(st[j + 2], a4.z, sa);
      sa = fmaf(st[j + 3], a4.w, sa);
    }
    float out = 0.f;
    #pragma unroll
    for (int q = 0; q < 16; ++q) {
      float4 w4 = *(const float4*)&lw[buf][q << 2];
      float4 k4 = *(const float4*)&lk[buf][q << 2];
      float4 b4 = *(const float4*)&lbo[buf][q << 2];
      float4 r4 = *(const float4*)&lr[buf][q << 2];
      int j = q << 2;
      st[j + 0] = st[j + 0] * w4.x + sa * b4.x + vi * k4.x; out = fmaf(st[j + 0], r4.x, out);
      st[j + 1] = st[j + 1] * w4.y + sa * b4.y + vi * k4.y; out = fmaf(st[j + 1], r4.y, out);
      st[j + 2] = st[j + 2] * w4.z + sa * b4.z + vi * k4.z; out = fmaf(st[j + 2], r4.z, out);
      st[j + 3] = st[j + 3] * w4.w + sa * b4.w + vi * k4.w; out = fmaf(st[j + 3], r4.w, out);
    }
    y[base + (size_t)t * CC] = f2bf(out);
    if (t + 1 < TT) {
      const int nb = buf ^ 1;
      lw[nb][lane]  = expf(-expf(nw));
      lk[nb][lane]  = nk;
      lao[nb][lane] = -nkk;
      lbo[nb][lane] = nkk * na;
      lr[nb][lane]  = nr;
      vi = nv;
    }
  }
}

// ---------------------------------------------------------------- GroupNorm + bonus + gate
__global__ __launch_bounds__(256)
void gn_k(u16* __restrict__ y, const u16* __restrict__ r,
          const u16* __restrict__ k, const u16* __restrict__ v,
          const u16* __restrict__ g, const float* __restrict__ rk_s,
          const float* __restrict__ gn_w, const float* __restrict__ gn_b)
{
  int tid = threadIdx.x, lane = tid & 63, wv = tid >> 6;
  int hidx = blockIdx.x * 4 + wv;
  int h = hidx & (HH - 1);
  int c = (h << 6) + lane;
  size_t base = ((size_t)hidx << 6) + lane;
  float yv = bf2f(y[base]), rv = bf2f(r[base]), kv = bf2f(k[base]);
  float vv = bf2f(v[base]), gv = bf2f(g[base]);
  float bsum = rv * kv * rk_s[c];
  float s1 = yv, s2 = yv * yv;
  for (int off = 32; off; off >>= 1) {
    s1 += __shfl_xor(s1, off, 64);
    s2 += __shfl_xor(s2, off, 64);
    bsum += __shfl_xor(bsum, off, 64);
  }
  float mu = s1 * (1.f / 64.f);
  float var = s2 * (1.f / 64.f) - mu * mu;
  float rstd = rsqrtf(var + 0.00064f);
  float z = (yv - mu) * rstd * gn_w[c] + gn_b[c];
  y[base] = f2bf((z + bsum * vv) * gv);
}

// ---------------------------------------------------------------- helpers
__global__ __launch_bounds__(256)
void copy_v0(const float* __restrict__ v0, float* __restrict__ out) {
  int idx = blockIdx.x * 256 + threadIdx.x;     // float4 granules
  ((float4*)out)[idx] = ((const float4*)v0)[idx];
}

__global__ __launch_bounds__(256)
void zero_out(float* __restrict__ out) {
  int idx = blockIdx.x * 256 + threadIdx.x;     // float4 granules
  ((float4*)out)[idx] = make_float4(0.f, 0.f, 0.f, 0.f);
}

// ----------------------------------------------------------------
extern "C" void kernel_launch(void* const* d_in, const int* in_sizes, int n_in,
                              void* d_out, int out_size, void* d_ws, size_t ws_size,
                              hipStream_t stream) {
  (void)n_in; (void)out_size;
  // Input order: setup_inputs() dict order (x, v0, xx_*, then ww_b, aa_b,
  // vv_b, kk_s, ka_s, then the w1/w2 mats, rk_s, W_*, gn_*). Disambiguate
  // against ARGS order at runtime: dict order has in_sizes[9] == C (aa_b),
  // ARGS order has in_sizes[9] == C*96 (ww_w1).
  const bool dictOrder = (in_sizes[9] == CC);
  int IX[28];
  if (dictOrder) {
    const int m[28] = {0,1,2,3,4,5,6,7, 8,13,14, 9,15,16, 10,17,18, 19,20,
                       11,12,21, 22,23,24,25, 26,27};
    for (int i = 0; i < 28; ++i) IX[i] = m[i];
  } else {
    for (int i = 0; i < 28; ++i) IX[i] = i;
  }
  const float* x     = (const float*)d_in[IX[0]];
  const float* v0    = (const float*)d_in[IX[1]];
  const float* xx_r  = (const float*)d_in[IX[2]];
  const float* xx_w  = (const float*)d_in[IX[3]];
  const float* xx_k  = (const float*)d_in[IX[4]];
  const float* xx_v  = (const float*)d_in[IX[5]];
  const float* xx_a  = (const float*)d_in[IX[6]];
  const float* xx_g  = (const float*)d_in[IX[7]];
  const float* ww_b  = (const float*)d_in[IX[8]];
  const float* ww_w1 = (const float*)d_in[IX[9]];
  const float* ww_w2 = (const float*)d_in[IX[10]];
  const float* aa_b  = (const float*)d_in[IX[11]];
  const float* aa_w1 = (const float*)d_in[IX[12]];
  const float* aa_w2 = (const float*)d_in[IX[13]];
  const float* vv_b  = (const float*)d_in[IX[14]];
  const float* vv_w1 = (const float*)d_in[IX[15]];
  const float* vv_w2 = (const float*)d_in[IX[16]];
  const float* gg_w1 = (const float*)d_in[IX[17]];
  const float* gg_w2 = (const float*)d_in[IX[18]];
  const float* kk_s  = (const float*)d_in[IX[19]];
  const float* ka_s  = (const float*)d_in[IX[20]];
  const float* rk_s  = (const float*)d_in[IX[21]];
  const float* W_r   = (const float*)d_in[IX[22]];
  const float* W_k   = (const float*)d_in[IX[23]];
  const float* W_v   = (const float*)d_in[IX[24]];
  const float* W_o   = (const float*)d_in[IX[25]];
  const float* gn_w  = (const float*)d_in[IX[26]];
  const float* gn_b  = (const float*)d_in[IX[27]];

  const size_t NBTC = (size_t)BT * CC;           // 4,194,304 elements
  dim3 blk(256);
  const int grid4f = (int)(NBTC / 4 / 256);      // float4 granules over NBTC

  // ws guard (kept as insurance; round-3 behavior implies ws_size >= need).
  const size_t WS_NEED = 7 * NBTC * sizeof(u16);
  float* outF = (float*)d_out;
  if (ws_size < WS_NEED || d_ws == nullptr) {
    zero_out<<<grid4f, blk, 0, stream>>>(outF);
    copy_v0<<<grid4f, blk, 0, stream>>>(v0, outF + NBTC);
    return;
  }

  // Region map (each NBTC bf16 = 8 MiB):
  // R0=r (early: h1 scratch)  R1=k  R2=v  R3=kk (early: fp32 partY; late: h2)
  // R4=a (late: g)  R5=w_raw (late: fp32 partG)  R6=mix staging
  u16* W16   = (u16*)d_ws;
  u16* ws_r  = W16 + 0 * NBTC;
  u16* ws_k  = W16 + 1 * NBTC;
  u16* ws_v  = W16 + 2 * NBTC;
  u16* ws_kk = W16 + 3 * NBTC;
  u16* ws_a  = W16 + 4 * NBTC;
  u16* ws_w  = W16 + 5 * NBTC;
  u16* ws_mix= W16 + 6 * NBTC;
  float* partY = (float*)ws_kk;   // pre-kkprep fp32 partial sums (8 MiB)
  float* partG = (float*)ws_w;    // post-rec g-path fp32 partials (8 MiB)
  u16* h1 = ws_r;                 // small hidden (<= BT*96), dead before r-gemm
  u16* h2 = ws_kk;                // g-path hidden (BT*256), post-rec
  u16* ws_g = ws_a;               // gate, post-rec
  u16* ws_y = (u16*)(outF + NBTC);// y (bf16) in the v0 output slot until the end

  const int gridMix = (BT * CC) / 256;           // 16384
  dim3 gBig(32, 32, 1);

  // ---- w path: w_raw = -softplus(-(ww_b + tanh(xw@ww_w1)@ww_w2)) - 0.5
  mix_k<<<gridMix, blk, 0, stream>>>(x, xx_w, ws_mix);
  gemm_k<EPI_PART><<<dim3(32, 2, 8), blk, 0, stream>>>(ws_mix, ww_w1, partY, nullptr,
      BT, 96, 2048, 256, 128, nullptr, nullptr, nullptr);
  reduce_k<<<(BT * 96 + 255) / 256, blk, 0, stream>>>(partY, h1, BT, 96, 128, 8, 1);
  gemm_k<EPI_BIAS_SP><<<gBig, blk, 0, stream>>>(h1, ww_w2, nullptr, ws_w,
      BT, 2048, 96, 96, 2048, ww_b, nullptr, nullptr);

  // ---- a path: a = sigmoid(aa_b + (xa@aa_w1)@aa_w2)
  mix_k<<<gridMix, blk, 0, stream>>>(x, xx_a, ws_mix);
  gemm_k<EPI_PART><<<dim3(32, 2, 8), blk, 0, stream>>>(ws_mix, aa_w1, partY, nullptr,
      BT, 96, 2048, 256, 128, nullptr, nullptr, nullptr);
  reduce_k<<<(BT * 96 + 255) / 256, blk, 0, stream>>>(partY, h1, BT, 96, 128, 8, 0);
  gemm_k<EPI_BIAS_SIG><<<gBig, blk, 0, stream>>>(h1, aa_w2, nullptr, ws_a,
      BT, 2048, 96, 96, 2048, aa_b, nullptr, nullptr);

  // ---- v path: v = xv@W_v, then v-mix with v0
  mix_k<<<gridMix, blk, 0, stream>>>(x, xx_v, ws_mix);
  gemm_k<EPI_BF><<<gBig, blk, 0, stream>>>(ws_mix, W_v, nullptr, ws_v,
      BT, 2048, 2048, 2048, 2048, nullptr, nullptr, nullptr);
  gemm_k<EPI_PART><<<dim3(32, 1, 8), blk, 0, stream>>>(ws_mix, vv_w1, partY, nullptr,
      BT, 64, 2048, 256, 64, nullptr, nullptr, nullptr);
  reduce_k<<<(BT * 64 + 255) / 256, blk, 0, stream>>>(partY, h1, BT, 64, 64, 8, 0);
  gemm_k<EPI_VMIX><<<gBig, blk, 0, stream>>>(h1, vv_w2, nullptr, ws_v,
      BT, 2048, 64, 64, 2048, vv_b, ws_v, v0);

  // ---- k path
  mix_k<<<gridMix, blk, 0, stream>>>(x, xx_k, ws_mix);
  gemm_k<EPI_BF><<<gBig, blk, 0, stream>>>(ws_mix, W_k, nullptr, ws_k,
      BT, 2048, 2048, 2048, 2048, nullptr, nullptr, nullptr);

  // ---- r path (overwrites h1 scratch, already consumed)
  mix_k<<<gridMix, blk, 0, stream>>>(x, xx_r, ws_mix);
  gemm_k<EPI_BF><<<gBig, blk, 0, stream>>>(ws_mix, W_r, nullptr, ws_r,
      BT, 2048, 2048, 2048, 2048, nullptr, nullptr, nullptr);

  // ---- kk / k-final
  kkprep_k<<<BT * HH / 4, blk, 0, stream>>>(ws_k, ws_a, kk_s, ka_s, ws_kk, ws_k);

  // ---- recurrence: y (bf16) into the v0 output slot
  rec_k<<<BB * HH, dim3(64), 0, stream>>>(ws_r, ws_w, ws_k, ws_v, ws_kk, ws_a, ws_y);

  // ---- g path (reuses dead w/kk/a regions)
  mix_k<<<gridMix, blk, 0, stream>>>(x, xx_g, ws_mix);
  gemm_k<EPI_PART><<<dim3(32, 4, 4), blk, 0, stream>>>(ws_mix, gg_w1, partG, nullptr,
      BT, 256, 2048, 512, 256, nullptr, nullptr, nullptr);
  reduce_k<<<(BT * 256 + 255) / 256, blk, 0, stream>>>(partG, h2, BT, 256, 256, 4, 2);
  gemm_k<EPI_BF><<<gBig, blk, 0, stream>>>(h2, gg_w2, nullptr, ws_g,
      BT, 2048, 256, 256, 2048, nullptr, nullptr, nullptr);

  // ---- groupnorm + bonus + gate (in place on y)
  gn_k<<<BT * HH / 4, blk, 0, stream>>>(ws_y, ws_r, ws_k, ws_v, ws_g,
                                        rk_s, gn_w, gn_b);

  // ---- final projection, fp32 into output 0
  gemm_k<EPI_F32><<<gBig, blk, 0, stream>>>(ws_y, W_o, outF, nullptr,
      BT, 2048, 2048, 2048, 2048, nullptr, nullptr, nullptr);

  // ---- v0 passthrough (overwrites the y scratch slot, last)
  copy_v0<<<grid4f, blk, 0, stream>>>(v0, outF + NBTC);
}

// Round 5
// 1928.811 us; speedup vs baseline: 1.2153x; 1.2153x over previous
//
#include <hip/hip_runtime.h>
#include <hip/hip_bf16.h>
#include <math.h>

typedef unsigned short u16;

#define BB 2
#define TT 1024
#define CC 2048
#define HH 32
#define BT (BB*TT)

// Inputs/outputs are fp32 (per reference dtypes). Intermediates in ws are
// bf16 (7 regions x NBTC = 56 MiB; ws_size >= that, established round 3).
// fp32 only in registers (GEMM accum, recurrence state, GN stats) and for
// K-split partials overlapping dead bf16 regions. y scratch lives in the
// second output slot (v0 slot) until copy_v0 overwrites it at the end.

__device__ __forceinline__ float bf2f(u16 u) {
  return __uint_as_float(((unsigned int)u) << 16);
}
__device__ __forceinline__ u16 f2bf(float f) {
  unsigned int x = __float_as_uint(f);
  x += 0x7fffu + ((x >> 16) & 1u);
  return (u16)(x >> 16);
}

// ---------------------------------------------------------------- mix kernel
// out[b,t,c] = x + (x_{t-1} - x) * s[c]   (zero pad at t==0), bf16 out
__global__ __launch_bounds__(256)
void mix_k(const float* __restrict__ x, const float* __restrict__ s,
           u16* __restrict__ out) {
  int idx = blockIdx.x * 256 + threadIdx.x;       // over BT*C
  int c = idx & (CC - 1);
  int t = (idx >> 11) & (TT - 1);                 // C = 2^11, T = 2^10
  float xv = x[idx];
  float xp = (t == 0) ? 0.f : x[idx - CC];
  out[idx] = f2bf(xv + (xp - xv) * s[c]);
}

// ---------------------------------------------------------------- GEMM
// C[M,N] = A[M,K](bf16 ws, pitch K) * W[K,N](fp32 input, pitch N), fp32 accum.
// tile 64x64x16, 256 threads, 4x4 per thread. Epilogue templated.
enum { EPI_PART = 0, EPI_BF = 1, EPI_F32 = 2, EPI_BIAS_SP = 3,
       EPI_BIAS_SIG = 4, EPI_VMIX = 5 };

template<int EPI>
__global__ __launch_bounds__(256)
void gemm_k(const u16* __restrict__ A, const float* __restrict__ W,
            float* __restrict__ outF, u16* __restrict__ outB,
            int M, int N, int K, int kchunk, int NP,
            const float* __restrict__ bias, const u16* __restrict__ p1,
            const float* __restrict__ p2)
{
  __shared__ alignas(16) float As[16][68];
  __shared__ alignas(16) float Bs[16][68];
  const int m0 = blockIdx.x * 64;
  const int n0 = blockIdx.y * 64;
  const int kz = blockIdx.z;
  const int k0base = kz * kchunk;
  const int tid = threadIdx.x;
  const int tx = tid & 15, ty = tid >> 4;
  float acc[4][4] = {{0.f}};
  const int a_m = tid >> 2;
  const int a_k = (tid & 3) << 2;
  const int b_k = tid >> 4;
  const int b_n = (tid & 15) << 2;
  const int niters = kchunk >> 4;
  for (int it = 0; it < niters; ++it) {
    const int k0 = k0base + (it << 4);
    float4 av;
    {
      ushort4 u = *(const ushort4*)(A + (size_t)(m0 + a_m) * K + (k0 + a_k));
      av = make_float4(bf2f(u.x), bf2f(u.y), bf2f(u.z), bf2f(u.w));
    }
    float4 bv;
    {
      int gn = n0 + b_n;
      const float* wp = W + (size_t)(k0 + b_k) * N + gn;
      if (gn + 3 < N) {
        bv = *(const float4*)wp;
      } else {
        bv.x = (gn + 0 < N) ? wp[0] : 0.f;
        bv.y = (gn + 1 < N) ? wp[1] : 0.f;
        bv.z = (gn + 2 < N) ? wp[2] : 0.f;
        bv.w = (gn + 3 < N) ? wp[3] : 0.f;
      }
    }
    __syncthreads();
    As[a_k + 0][a_m] = av.x; As[a_k + 1][a_m] = av.y;
    As[a_k + 2][a_m] = av.z; As[a_k + 3][a_m] = av.w;
    Bs[b_k][b_n + 0] = bv.x; Bs[b_k][b_n + 1] = bv.y;
    Bs[b_k][b_n + 2] = bv.z; Bs[b_k][b_n + 3] = bv.w;
    __syncthreads();
    #pragma unroll
    for (int kk = 0; kk < 16; ++kk) {
      float4 a4 = *(const float4*)&As[kk][ty << 2];
      float4 b4 = *(const float4*)&Bs[kk][tx << 2];
      float ar[4] = {a4.x, a4.y, a4.z, a4.w};
      float br[4] = {b4.x, b4.y, b4.z, b4.w};
      #pragma unroll
      for (int i = 0; i < 4; ++i)
        #pragma unroll
        for (int j = 0; j < 4; ++j)
          acc[i][j] = fmaf(ar[i], br[j], acc[i][j]);
    }
  }
  #pragma unroll
  for (int i = 0; i < 4; ++i) {
    int gm = m0 + (ty << 2) + i;
    #pragma unroll
    for (int j = 0; j < 4; ++j) {
      int gn = n0 + (tx << 2) + j;
      if (gn >= N) continue;
      float r = acc[i][j];
      size_t idx = (size_t)gm * N + gn;
      if (EPI == EPI_PART) {
        outF[((size_t)kz * M + gm) * NP + gn] = r;
      } else if (EPI == EPI_BF) {
        outB[idx] = f2bf(r);
      } else if (EPI == EPI_F32) {
        outF[idx] = r;
      } else if (EPI == EPI_BIAS_SP) {
        // -softplus(-(bias + r)) - 0.5, numerically stable
        float u = bias[gn] + r;
        float z = -u;
        float sp = fmaxf(z, 0.f) + log1pf(expf(-fabsf(z)));
        outB[idx] = f2bf(-sp - 0.5f);
      } else if (EPI == EPI_BIAS_SIG) {
        float u = bias[gn] + r;
        outB[idx] = f2bf(1.f / (1.f + expf(-u)));
      } else if (EPI == EPI_VMIX) {
        float u = bias[gn] + r;
        float sg = 1.f / (1.f + expf(-u));
        float v = bf2f(p1[idx]);
        float v0v = p2[idx];
        outB[idx] = f2bf(v + (v0v - v) * sg);
      }
    }
  }
}

// ---------------------------------------------------------------- K-split reduce
__global__ __launch_bounds__(256)
void reduce_k(const float* __restrict__ part, u16* __restrict__ out,
              int M, int D, int NP, int nz, int act)
{
  int idx = blockIdx.x * 256 + threadIdx.x;
  if (idx >= M * D) return;
  int t = idx / D, n = idx - t * D;
  float s = 0.f;
  for (int z = 0; z < nz; ++z) s += part[((size_t)z * M + t) * NP + n];
  if (act == 1) s = tanhf(s);
  else if (act == 2) s = 1.f / (1.f + expf(-s));
  out[idx] = f2bf(s);
}

// ---------------------------------------------------------------- kk prep
// kk = normalize_per_head(k * kk_s); k <- k * (1 + (a-1)*ka_s)
__global__ __launch_bounds__(256)
void kkprep_k(const u16* __restrict__ k_in, const u16* __restrict__ a_in,
              const float* __restrict__ kk_s, const float* __restrict__ ka_s,
              u16* __restrict__ kk_out, u16* __restrict__ k_out)
{
  int tid = threadIdx.x;
  int lane = tid & 63;
  int wv = tid >> 6;
  int hidx = blockIdx.x * 4 + wv;               // 0 .. BT*H-1
  int h = hidx & (HH - 1);
  int c = (h << 6) + lane;
  size_t base = ((size_t)hidx << 6) + lane;
  float k = bf2f(k_in[base]);
  float kk = k * kk_s[c];
  float ss = kk * kk;
  for (int off = 32; off; off >>= 1) ss += __shfl_xor(ss, off, 64);
  float denom = fmaxf(sqrtf(ss), 1e-12f);
  kk_out[base] = f2bf(kk / denom);
  float a = bf2f(a_in[base]);
  k_out[base] = f2bf(k * (1.f + (a - 1.f) * ka_s[c]));
}

// ---------------------------------------------------------------- RWKV7 recurrence
// Wave-per-row decomposition: state rows (b,h,i) are fully independent.
// One 64-lane wave owns row i of head (b,h); lane = j (key dim). State is
// 1 VGPR/lane; sa and y are 6-level __shfl_xor butterflies. No LDS, no
// __syncthreads. 4096 waves total (1024 blocks x 4 waves) = 4 waves/SIMD
// across all 256 CUs. The 4 waves of a block share (b,h) so their vector
// loads hit the same cache lines. Next-step operands register-prefetched.
__global__ __launch_bounds__(256)
void rec_k(const u16* __restrict__ r, const u16* __restrict__ w,
           const u16* __restrict__ k, const u16* __restrict__ v,
           const u16* __restrict__ kk, const u16* __restrict__ a,
           u16* __restrict__ y)
{
  const int gw = blockIdx.x * 4 + (threadIdx.x >> 6);   // global wave = row id
  const int lane = threadIdx.x & 63;                    // j
  const int bh = gw >> 6;                               // 0..B*H-1
  const int i  = gw & 63;                               // value-dim row
  const int b = bh >> 5, h = bh & (HH - 1);
  const size_t base0 = ((size_t)b * TT) * CC + (h << 6);
  size_t vecbase = base0 + lane;                        // [b,t,h,lane]
  size_t vbase   = base0 + i;                           // v,y: [b,t,h,i]
  float s = 0.f;
  // prefetch t = 0
  float pw = bf2f(w[vecbase]);
  float pk = bf2f(k[vecbase]);
  float pkk = bf2f(kk[vecbase]);
  float pa = bf2f(a[vecbase]);
  float pr = bf2f(r[vecbase]);
  float pv = bf2f(v[vbase]);
  for (int t = 0; t < TT; ++t) {
    const float cw = expf(-expf(pw));
    const float ck = pk, ckk = pkk, ca = pa, cr = pr, cv = pv;
    if (t + 1 < TT) {
      const size_t nb = vecbase + (size_t)(t + 1) * CC;
      pw = bf2f(w[nb]); pk = bf2f(k[nb]); pkk = bf2f(kk[nb]);
      pa = bf2f(a[nb]); pr = bf2f(r[nb]);
      pv = bf2f(v[vbase + (size_t)(t + 1) * CC]);
    }
    // sa = sum_j S[i,j] * (-kk_j)   (pre-update state)
    float sa = s * (-ckk);
    sa += __shfl_xor(sa, 1, 64);
    sa += __shfl_xor(sa, 2, 64);
    sa += __shfl_xor(sa, 4, 64);
    sa += __shfl_xor(sa, 8, 64);
    sa += __shfl_xor(sa, 16, 64);
    sa += __shfl_xor(sa, 32, 64);
    // S[i,j] = S[i,j]*w_j + sa*(kk_j*a_j) + v_i*k_j
    s = s * cw + sa * (ckk * ca) + cv * ck;
    // y[i] = sum_j S[i,j] * r_j
    float o = s * cr;
    o += __shfl_xor(o, 1, 64);
    o += __shfl_xor(o, 2, 64);
    o += __shfl_xor(o, 4, 64);
    o += __shfl_xor(o, 8, 64);
    o += __shfl_xor(o, 16, 64);
    o += __shfl_xor(o, 32, 64);
    if (lane == 0) y[vbase + (size_t)t * CC] = f2bf(o);
  }
}

// ---------------------------------------------------------------- GroupNorm + bonus + gate
__global__ __launch_bounds__(256)
void gn_k(u16* __restrict__ y, const u16* __restrict__ r,
          const u16* __restrict__ k, const u16* __restrict__ v,
          const u16* __restrict__ g, const float* __restrict__ rk_s,
          const float* __restrict__ gn_w, const float* __restrict__ gn_b)
{
  int tid = threadIdx.x, lane = tid & 63, wv = tid >> 6;
  int hidx = blockIdx.x * 4 + wv;
  int h = hidx & (HH - 1);
  int c = (h << 6) + lane;
  size_t base = ((size_t)hidx << 6) + lane;
  float yv = bf2f(y[base]), rv = bf2f(r[base]), kv = bf2f(k[base]);
  float vv = bf2f(v[base]), gv = bf2f(g[base]);
  float bsum = rv * kv * rk_s[c];
  float s1 = yv, s2 = yv * yv;
  for (int off = 32; off; off >>= 1) {
    s1 += __shfl_xor(s1, off, 64);
    s2 += __shfl_xor(s2, off, 64);
    bsum += __shfl_xor(bsum, off, 64);
  }
  float mu = s1 * (1.f / 64.f);
  float var = s2 * (1.f / 64.f) - mu * mu;
  float rstd = rsqrtf(var + 0.00064f);
  float z = (yv - mu) * rstd * gn_w[c] + gn_b[c];
  y[base] = f2bf((z + bsum * vv) * gv);
}

// ---------------------------------------------------------------- helpers
__global__ __launch_bounds__(256)
void copy_v0(const float* __restrict__ v0, float* __restrict__ out) {
  int idx = blockIdx.x * 256 + threadIdx.x;     // float4 granules
  ((float4*)out)[idx] = ((const float4*)v0)[idx];
}

__global__ __launch_bounds__(256)
void zero_out(float* __restrict__ out) {
  int idx = blockIdx.x * 256 + threadIdx.x;     // float4 granules
  ((float4*)out)[idx] = make_float4(0.f, 0.f, 0.f, 0.f);
}

// ----------------------------------------------------------------
extern "C" void kernel_launch(void* const* d_in, const int* in_sizes, int n_in,
                              void* d_out, int out_size, void* d_ws, size_t ws_size,
                              hipStream_t stream) {
  (void)n_in; (void)out_size;
  // Input order: setup_inputs() dict order (x, v0, xx_*, then ww_b, aa_b,
  // vv_b, kk_s, ka_s, then the w1/w2 mats, rk_s, W_*, gn_*). Disambiguate
  // against ARGS order at runtime: dict order has in_sizes[9] == C (aa_b),
  // ARGS order has in_sizes[9] == C*96 (ww_w1).
  const bool dictOrder = (in_sizes[9] == CC);
  int IX[28];
  if (dictOrder) {
    const int m[28] = {0,1,2,3,4,5,6,7, 8,13,14, 9,15,16, 10,17,18, 19,20,
                       11,12,21, 22,23,24,25, 26,27};
    for (int i = 0; i < 28; ++i) IX[i] = m[i];
  } else {
    for (int i = 0; i < 28; ++i) IX[i] = i;
  }
  const float* x     = (const float*)d_in[IX[0]];
  const float* v0    = (const float*)d_in[IX[1]];
  const float* xx_r  = (const float*)d_in[IX[2]];
  const float* xx_w  = (const float*)d_in[IX[3]];
  const float* xx_k  = (const float*)d_in[IX[4]];
  const float* xx_v  = (const float*)d_in[IX[5]];
  const float* xx_a  = (const float*)d_in[IX[6]];
  const float* xx_g  = (const float*)d_in[IX[7]];
  const float* ww_b  = (const float*)d_in[IX[8]];
  const float* ww_w1 = (const float*)d_in[IX[9]];
  const float* ww_w2 = (const float*)d_in[IX[10]];
  const float* aa_b  = (const float*)d_in[IX[11]];
  const float* aa_w1 = (const float*)d_in[IX[12]];
  const float* aa_w2 = (const float*)d_in[IX[13]];
  const float* vv_b  = (const float*)d_in[IX[14]];
  const float* vv_w1 = (const float*)d_in[IX[15]];
  const float* vv_w2 = (const float*)d_in[IX[16]];
  const float* gg_w1 = (const float*)d_in[IX[17]];
  const float* gg_w2 = (const float*)d_in[IX[18]];
  const float* kk_s  = (const float*)d_in[IX[19]];
  const float* ka_s  = (const float*)d_in[IX[20]];
  const float* rk_s  = (const float*)d_in[IX[21]];
  const float* W_r   = (const float*)d_in[IX[22]];
  const float* W_k   = (const float*)d_in[IX[23]];
  const float* W_v   = (const float*)d_in[IX[24]];
  const float* W_o   = (const float*)d_in[IX[25]];
  const float* gn_w  = (const float*)d_in[IX[26]];
  const float* gn_b  = (const float*)d_in[IX[27]];

  const size_t NBTC = (size_t)BT * CC;           // 4,194,304 elements
  dim3 blk(256);
  const int grid4f = (int)(NBTC / 4 / 256);      // float4 granules over NBTC

  // ws guard (kept as insurance; round-3 behavior implies ws_size >= need).
  const size_t WS_NEED = 7 * NBTC * sizeof(u16);
  float* outF = (float*)d_out;
  if (ws_size < WS_NEED || d_ws == nullptr) {
    zero_out<<<grid4f, blk, 0, stream>>>(outF);
    copy_v0<<<grid4f, blk, 0, stream>>>(v0, outF + NBTC);
    return;
  }

  // Region map (each NBTC bf16 = 8 MiB):
  // R0=r (early: h1 scratch)  R1=k  R2=v  R3=kk (early: fp32 partY; late: h2)
  // R4=a (late: g)  R5=w_raw (late: fp32 partG)  R6=mix staging
  u16* W16   = (u16*)d_ws;
  u16* ws_r  = W16 + 0 * NBTC;
  u16* ws_k  = W16 + 1 * NBTC;
  u16* ws_v  = W16 + 2 * NBTC;
  u16* ws_kk = W16 + 3 * NBTC;
  u16* ws_a  = W16 + 4 * NBTC;
  u16* ws_w  = W16 + 5 * NBTC;
  u16* ws_mix= W16 + 6 * NBTC;
  float* partY = (float*)ws_kk;   // pre-kkprep fp32 partial sums (8 MiB)
  float* partG = (float*)ws_w;    // post-rec g-path fp32 partials (8 MiB)
  u16* h1 = ws_r;                 // small hidden (<= BT*96), dead before r-gemm
  u16* h2 = ws_kk;                // g-path hidden (BT*256), post-rec
  u16* ws_g = ws_a;               // gate, post-rec
  u16* ws_y = (u16*)(outF + NBTC);// y (bf16) in the v0 output slot until the end

  const int gridMix = (BT * CC) / 256;           // 16384
  dim3 gBig(32, 32, 1);

  // ---- w path: w_raw = -softplus(-(ww_b + tanh(xw@ww_w1)@ww_w2)) - 0.5
  mix_k<<<gridMix, blk, 0, stream>>>(x, xx_w, ws_mix);
  gemm_k<EPI_PART><<<dim3(32, 2, 8), blk, 0, stream>>>(ws_mix, ww_w1, partY, nullptr,
      BT, 96, 2048, 256, 128, nullptr, nullptr, nullptr);
  reduce_k<<<(BT * 96 + 255) / 256, blk, 0, stream>>>(partY, h1, BT, 96, 128, 8, 1);
  gemm_k<EPI_BIAS_SP><<<gBig, blk, 0, stream>>>(h1, ww_w2, nullptr, ws_w,
      BT, 2048, 96, 96, 2048, ww_b, nullptr, nullptr);

  // ---- a path: a = sigmoid(aa_b + (xa@aa_w1)@aa_w2)
  mix_k<<<gridMix, blk, 0, stream>>>(x, xx_a, ws_mix);
  gemm_k<EPI_PART><<<dim3(32, 2, 8), blk, 0, stream>>>(ws_mix, aa_w1, partY, nullptr,
      BT, 96, 2048, 256, 128, nullptr, nullptr, nullptr);
  reduce_k<<<(BT * 96 + 255) / 256, blk, 0, stream>>>(partY, h1, BT, 96, 128, 8, 0);
  gemm_k<EPI_BIAS_SIG><<<gBig, blk, 0, stream>>>(h1, aa_w2, nullptr, ws_a,
      BT, 2048, 96, 96, 2048, aa_b, nullptr, nullptr);

  // ---- v path: v = xv@W_v, then v-mix with v0
  mix_k<<<gridMix, blk, 0, stream>>>(x, xx_v, ws_mix);
  gemm_k<EPI_BF><<<gBig, blk, 0, stream>>>(ws_mix, W_v, nullptr, ws_v,
      BT, 2048, 2048, 2048, 2048, nullptr, nullptr, nullptr);
  gemm_k<EPI_PART><<<dim3(32, 1, 8), blk, 0, stream>>>(ws_mix, vv_w1, partY, nullptr,
      BT, 64, 2048, 256, 64, nullptr, nullptr, nullptr);
  reduce_k<<<(BT * 64 + 255) / 256, blk, 0, stream>>>(partY, h1, BT, 64, 64, 8, 0);
  gemm_k<EPI_VMIX><<<gBig, blk, 0, stream>>>(h1, vv_w2, nullptr, ws_v,
      BT, 2048, 64, 64, 2048, vv_b, ws_v, v0);

  // ---- k path
  mix_k<<<gridMix, blk, 0, stream>>>(x, xx_k, ws_mix);
  gemm_k<EPI_BF><<<gBig, blk, 0, stream>>>(ws_mix, W_k, nullptr, ws_k,
      BT, 2048, 2048, 2048, 2048, nullptr, nullptr, nullptr);

  // ---- r path (overwrites h1 scratch, already consumed)
  mix_k<<<gridMix, blk, 0, stream>>>(x, xx_r, ws_mix);
  gemm_k<EPI_BF><<<gBig, blk, 0, stream>>>(ws_mix, W_r, nullptr, ws_r,
      BT, 2048, 2048, 2048, 2048, nullptr, nullptr, nullptr);

  // ---- kk / k-final
  kkprep_k<<<BT * HH / 4, blk, 0, stream>>>(ws_k, ws_a, kk_s, ka_s, ws_kk, ws_k);

  // ---- recurrence: y (bf16) into the v0 output slot
  rec_k<<<(BB * HH * 64) / 4, blk, 0, stream>>>(ws_r, ws_w, ws_k, ws_v, ws_kk,
                                                ws_a, ws_y);

  // ---- g path (reuses dead w/kk/a regions)
  mix_k<<<gridMix, blk, 0, stream>>>(x, xx_g, ws_mix);
  gemm_k<EPI_PART><<<dim3(32, 4, 4), blk, 0, stream>>>(ws_mix, gg_w1, partG, nullptr,
      BT, 256, 2048, 512, 256, nullptr, nullptr, nullptr);
  reduce_k<<<(BT * 256 + 255) / 256, blk, 0, stream>>>(partG, h2, BT, 256, 256, 4, 2);
  gemm_k<EPI_BF><<<gBig, blk, 0, stream>>>(h2, gg_w2, nullptr, ws_g,
      BT, 2048, 256, 256, 2048, nullptr, nullptr, nullptr);

  // ---- groupnorm + bonus + gate (in place on y)
  gn_k<<<BT * HH / 4, blk, 0, stream>>>(ws_y, ws_r, ws_k, ws_v, ws_g,
                                        rk_s, gn_w, gn_b);

  // ---- final projection, fp32 into output 0
  gemm_k<EPI_F32><<<gBig, blk, 0, stream>>>(ws_y, W_o, outF, nullptr,
      BT, 2048, 2048, 2048, 2048, nullptr, nullptr, nullptr);

  // ---- v0 passthrough (overwrites the y scratch slot, last)
  copy_v0<<<grid4f, blk, 0, stream>>>(v0, outF + NBTC);
}

// Round 7
// 1185.573 us; speedup vs baseline: 1.9772x; 1.6269x over previous
//
#include <hip/hip_runtime.h>
#include <hip/hip_bf16.h>
#include <math.h>

typedef unsigned short u16;
typedef __attribute__((ext_vector_type(8))) unsigned short us8;
typedef __attribute__((ext_vector_type(8))) short s8v;   // mfma bf16 operand (4 VGPRs)
typedef __attribute__((ext_vector_type(4))) float f4v;   // mfma accum

#define BB 2
#define TT 1024
#define CC 2048
#define HH 32
#define BT (BB*TT)

// Inputs/outputs fp32. ws intermediates bf16: 7 regions x NBTC u16 = 112 MiB
// (ws_size >= that, established rounds 4/5). Weights cvt-transposed to bf16
// [N][K] just-in-time into dead regions for the MFMA GEMMs.

__device__ __forceinline__ float bf2f(u16 u) {
  return __uint_as_float(((unsigned int)u) << 16);
}
__device__ __forceinline__ u16 f2bf(float f) {
  unsigned int x = __float_as_uint(f);
  x += 0x7fffu + ((x >> 16) & 1u);
  return (u16)(x >> 16);
}

// ---------------------------------------------------------------- mix kernel
__global__ __launch_bounds__(256)
void mix_k(const float* __restrict__ x, const float* __restrict__ s,
           u16* __restrict__ out) {
  int idx = blockIdx.x * 256 + threadIdx.x;       // over BT*C
  int c = idx & (CC - 1);
  int t = (idx >> 11) & (TT - 1);
  float xv = x[idx];
  float xp = (t == 0) ? 0.f : x[idx - CC];
  out[idx] = f2bf(xv + (xp - xv) * s[c]);
}

// ---------------------------------------------------------------- weight cvt-transpose
// W fp32 [K][N] -> Wt bf16 [N][K]. 32x32 tiles, 256 threads.
__global__ __launch_bounds__(256)
void wt_k(const float* __restrict__ W, u16* __restrict__ Wt, int K, int N) {
  __shared__ u16 tile[32][36];
  const int k0 = blockIdx.x * 32, n0 = blockIdx.y * 32;
  const int tid = threadIdx.x;
  const int r = tid >> 3, c4 = (tid & 7) << 2;
  float4 v = *(const float4*)(W + (size_t)(k0 + r) * N + n0 + c4);
  tile[r][c4 + 0] = f2bf(v.x); tile[r][c4 + 1] = f2bf(v.y);
  tile[r][c4 + 2] = f2bf(v.z); tile[r][c4 + 3] = f2bf(v.w);
  __syncthreads();
  ushort4 o;
  o.x = tile[c4 + 0][r]; o.y = tile[c4 + 1][r];
  o.z = tile[c4 + 2][r]; o.w = tile[c4 + 3][r];
  *(ushort4*)(Wt + (size_t)(n0 + r) * K + k0 + c4) = o;
}

// ---------------------------------------------------------------- MFMA GEMM
// C[M,N] = A[M,K](bf16, pitch K) * B(given as Bt[N][K] bf16), fp32 accum.
// Block tile 128x128, BK=32, 4 waves (2x2), wave tile 64x64 = 4x4 frags of
// 16x16x32. Full staging: 256 threads x 2 us8 per operand tile.
enum { EPI_BF = 0, EPI_F32 = 1, EPI_BIAS_SP = 2, EPI_BIAS_SIG = 3,
       EPI_VMIX = 4 };

template<int EPI>
__global__ __launch_bounds__(256)
void mgemm_k(const u16* __restrict__ A, const u16* __restrict__ Bt,
             float* __restrict__ outF, u16* __restrict__ outB,
             int M, int N, int K,
             const float* __restrict__ bias, const u16* __restrict__ p1,
             const float* __restrict__ p2)
{
  __shared__ alignas(16) u16 As[128][40];   // 32 k + 8 pad (80 B row stride)
  __shared__ alignas(16) u16 Bs[128][40];
  const int m0 = blockIdx.x * 128;
  const int n0 = blockIdx.y * 128;
  const int tid = threadIdx.x;
  const int lane = tid & 63;
  const int wid = tid >> 6;
  const int wr = wid >> 1, wc = wid & 1;        // wave quadrant (2x2)
  const int srow = tid >> 1;                    // staging row (0..127)
  const int scol = (tid & 1) << 4;              // staging k-col (0 or 16)
  f4v acc[4][4];
  #pragma unroll
  for (int i = 0; i < 4; ++i)
    #pragma unroll
    for (int j = 0; j < 4; ++j) acc[i][j] = f4v{0.f, 0.f, 0.f, 0.f};

  const int l15 = lane & 15;
  const int lk = (lane >> 4) << 3;              // k offset within BK (0,8,16,24)
  const int nkt = K >> 5;
  for (int kt = 0; kt < nkt; ++kt) {
    const int k0 = kt << 5;
    const u16* ap = A  + (size_t)(m0 + srow) * K + k0 + scol;
    const u16* bp = Bt + (size_t)(n0 + srow) * K + k0 + scol;
    us8 a0 = *(const us8*)(ap);
    us8 a1 = *(const us8*)(ap + 8);
    us8 b0 = *(const us8*)(bp);
    us8 b1 = *(const us8*)(bp + 8);
    __syncthreads();                            // prev compute done
    *(us8*)&As[srow][scol]     = a0;
    *(us8*)&As[srow][scol + 8] = a1;
    *(us8*)&Bs[srow][scol]     = b0;
    *(us8*)&Bs[srow][scol + 8] = b1;
    __syncthreads();
    s8v af[4], bfr[4];
    #pragma unroll
    for (int i = 0; i < 4; ++i)
      af[i] = *(const s8v*)&As[wr * 64 + i * 16 + l15][lk];
    #pragma unroll
    for (int j = 0; j < 4; ++j)
      bfr[j] = *(const s8v*)&Bs[wc * 64 + j * 16 + l15][lk];
    #pragma unroll
    for (int i = 0; i < 4; ++i)
      #pragma unroll
      for (int j = 0; j < 4; ++j)
        acc[i][j] = __builtin_amdgcn_mfma_f32_16x16x32_bf16(af[i], bfr[j],
                                                            acc[i][j], 0, 0, 0);
  }
  // C/D layout: col = lane&15, row = (lane>>4)*4 + q  (m89-verified)
  const int rbase = m0 + wr * 64 + ((lane >> 4) << 2);
  const int cbase = n0 + wc * 64 + l15;
  #pragma unroll
  for (int i = 0; i < 4; ++i) {
    #pragma unroll
    for (int j = 0; j < 4; ++j) {
      f4v c = acc[i][j];
      const int col = cbase + j * 16;
      #pragma unroll
      for (int q = 0; q < 4; ++q) {
        const int row = rbase + i * 16 + q;
        const size_t idx = (size_t)row * N + col;
        const float r = c[q];
        if (EPI == EPI_BF) {
          outB[idx] = f2bf(r);
        } else if (EPI == EPI_F32) {
          outF[idx] = r;
        } else if (EPI == EPI_BIAS_SP) {
          float u = bias[col] + r;
          float z = -u;
          float sp = fmaxf(z, 0.f) + log1pf(expf(-fabsf(z)));
          outB[idx] = f2bf(-sp - 0.5f);
        } else if (EPI == EPI_BIAS_SIG) {
          float u = bias[col] + r;
          outB[idx] = f2bf(1.f / (1.f + expf(-u)));
        } else if (EPI == EPI_VMIX) {
          float u = bias[col] + r;
          float sg = 1.f / (1.f + expf(-u));
          float v = bf2f(p1[idx]);
          float v0v = p2[idx];
          outB[idx] = f2bf(v + (v0v - v) * sg);
        }
      }
    }
  }
}

// ---------------------------------------------------------------- SIMT GEMM (skinny w1 paths)
__global__ __launch_bounds__(256)
void gemm_part_k(const u16* __restrict__ A, const float* __restrict__ W,
                 float* __restrict__ outF, int M, int N, int K, int kchunk,
                 int NP)
{
  __shared__ alignas(16) float As[16][68];
  __shared__ alignas(16) float Bs[16][68];
  const int m0 = blockIdx.x * 64;
  const int n0 = blockIdx.y * 64;
  const int kz = blockIdx.z;
  const int k0base = kz * kchunk;
  const int tid = threadIdx.x;
  const int tx = tid & 15, ty = tid >> 4;
  float acc[4][4] = {{0.f}};
  const int a_m = tid >> 2;
  const int a_k = (tid & 3) << 2;
  const int b_k = tid >> 4;
  const int b_n = (tid & 15) << 2;
  const int niters = kchunk >> 4;
  for (int it = 0; it < niters; ++it) {
    const int k0 = k0base + (it << 4);
    float4 av;
    {
      ushort4 u = *(const ushort4*)(A + (size_t)(m0 + a_m) * K + (k0 + a_k));
      av = make_float4(bf2f(u.x), bf2f(u.y), bf2f(u.z), bf2f(u.w));
    }
    float4 bv;
    {
      int gn = n0 + b_n;
      const float* wp = W + (size_t)(k0 + b_k) * N + gn;
      if (gn + 3 < N) {
        bv = *(const float4*)wp;
      } else {
        bv.x = (gn + 0 < N) ? wp[0] : 0.f;
        bv.y = (gn + 1 < N) ? wp[1] : 0.f;
        bv.z = (gn + 2 < N) ? wp[2] : 0.f;
        bv.w = (gn + 3 < N) ? wp[3] : 0.f;
      }
    }
    __syncthreads();
    As[a_k + 0][a_m] = av.x; As[a_k + 1][a_m] = av.y;
    As[a_k + 2][a_m] = av.z; As[a_k + 3][a_m] = av.w;
    Bs[b_k][b_n + 0] = bv.x; Bs[b_k][b_n + 1] = bv.y;
    Bs[b_k][b_n + 2] = bv.z; Bs[b_k][b_n + 3] = bv.w;
    __syncthreads();
    #pragma unroll
    for (int kk = 0; kk < 16; ++kk) {
      float4 a4 = *(const float4*)&As[kk][ty << 2];
      float4 b4 = *(const float4*)&Bs[kk][tx << 2];
      float ar[4] = {a4.x, a4.y, a4.z, a4.w};
      float br[4] = {b4.x, b4.y, b4.z, b4.w};
      #pragma unroll
      for (int i = 0; i < 4; ++i)
        #pragma unroll
        for (int j = 0; j < 4; ++j)
          acc[i][j] = fmaf(ar[i], br[j], acc[i][j]);
    }
  }
  #pragma unroll
  for (int i = 0; i < 4; ++i) {
    int gm = m0 + (ty << 2) + i;
    #pragma unroll
    for (int j = 0; j < 4; ++j) {
      int gn = n0 + (tx << 2) + j;
      if (gn >= N) continue;
      outF[((size_t)kz * M + gm) * NP + gn] = acc[i][j];
    }
  }
}

// ---------------------------------------------------------------- K-split reduce
__global__ __launch_bounds__(256)
void reduce_k(const float* __restrict__ part, u16* __restrict__ out,
              int M, int D, int NP, int nz, int act)
{
  int idx = blockIdx.x * 256 + threadIdx.x;
  if (idx >= M * D) return;
  int t = idx / D, n = idx - t * D;
  float s = 0.f;
  for (int z = 0; z < nz; ++z) s += part[((size_t)z * M + t) * NP + n];
  if (act == 1) s = tanhf(s);
  else if (act == 2) s = 1.f / (1.f + expf(-s));
  out[idx] = f2bf(s);
}

// ---------------------------------------------------------------- kk prep
__global__ __launch_bounds__(256)
void kkprep_k(const u16* __restrict__ k_in, const u16* __restrict__ a_in,
              const float* __restrict__ kk_s, const float* __restrict__ ka_s,
              u16* __restrict__ kk_out, u16* __restrict__ k_out)
{
  int tid = threadIdx.x;
  int lane = tid & 63;
  int wv = tid >> 6;
  int hidx = blockIdx.x * 4 + wv;
  int h = hidx & (HH - 1);
  int c = (h << 6) + lane;
  size_t base = ((size_t)hidx << 6) + lane;
  float k = bf2f(k_in[base]);
  float kk = k * kk_s[c];
  float ss = kk * kk;
  for (int off = 32; off; off >>= 1) ss += __shfl_xor(ss, off, 64);
  float denom = fmaxf(sqrtf(ss), 1e-12f);
  kk_out[base] = f2bf(kk / denom);
  float a = bf2f(a_in[base]);
  k_out[base] = f2bf(k * (1.f + (a - 1.f) * ka_s[c]));
}

// ---------------------------------------------------------------- RWKV7 recurrence
__global__ __launch_bounds__(256)
void rec_k(const u16* __restrict__ r, const u16* __restrict__ w,
           const u16* __restrict__ k, const u16* __restrict__ v,
           const u16* __restrict__ kk, const u16* __restrict__ a,
           u16* __restrict__ y)
{
  const int gw = blockIdx.x * 4 + (threadIdx.x >> 6);
  const int lane = threadIdx.x & 63;
  const int bh = gw >> 6;
  const int i  = gw & 63;
  const int b = bh >> 5, h = bh & (HH - 1);
  const size_t base0 = ((size_t)b * TT) * CC + (h << 6);
  size_t vecbase = base0 + lane;
  size_t vbase   = base0 + i;
  float s = 0.f;
  float pw = bf2f(w[vecbase]);
  float pk = bf2f(k[vecbase]);
  float pkk = bf2f(kk[vecbase]);
  float pa = bf2f(a[vecbase]);
  float pr = bf2f(r[vecbase]);
  float pv = bf2f(v[vbase]);
  for (int t = 0; t < TT; ++t) {
    const float cw = __expf(-__expf(pw));
    const float ck = pk, ckk = pkk, ca = pa, cr = pr, cv = pv;
    if (t + 1 < TT) {
      const size_t nb = vecbase + (size_t)(t + 1) * CC;
      pw = bf2f(w[nb]); pk = bf2f(k[nb]); pkk = bf2f(kk[nb]);
      pa = bf2f(a[nb]); pr = bf2f(r[nb]);
      pv = bf2f(v[vbase + (size_t)(t + 1) * CC]);
    }
    float sa = s * (-ckk);
    sa += __shfl_xor(sa, 1, 64);
    sa += __shfl_xor(sa, 2, 64);
    sa += __shfl_xor(sa, 4, 64);
    sa += __shfl_xor(sa, 8, 64);
    sa += __shfl_xor(sa, 16, 64);
    sa += __shfl_xor(sa, 32, 64);
    s = s * cw + sa * (ckk * ca) + cv * ck;
    float o = s * cr;
    o += __shfl_xor(o, 1, 64);
    o += __shfl_xor(o, 2, 64);
    o += __shfl_xor(o, 4, 64);
    o += __shfl_xor(o, 8, 64);
    o += __shfl_xor(o, 16, 64);
    o += __shfl_xor(o, 32, 64);
    if (lane == 0) y[vbase + (size_t)t * CC] = f2bf(o);
  }
}

// ---------------------------------------------------------------- GroupNorm + bonus + gate
__global__ __launch_bounds__(256)
void gn_k(u16* __restrict__ y, const u16* __restrict__ r,
          const u16* __restrict__ k, const u16* __restrict__ v,
          const u16* __restrict__ g, const float* __restrict__ rk_s,
          const float* __restrict__ gn_w, const float* __restrict__ gn_b)
{
  int tid = threadIdx.x, lane = tid & 63, wv = tid >> 6;
  int hidx = blockIdx.x * 4 + wv;
  int h = hidx & (HH - 1);
  int c = (h << 6) + lane;
  size_t base = ((size_t)hidx << 6) + lane;
  float yv = bf2f(y[base]), rv = bf2f(r[base]), kv = bf2f(k[base]);
  float vv = bf2f(v[base]), gv = bf2f(g[base]);
  float bsum = rv * kv * rk_s[c];
  float s1 = yv, s2 = yv * yv;
  for (int off = 32; off; off >>= 1) {
    s1 += __shfl_xor(s1, off, 64);
    s2 += __shfl_xor(s2, off, 64);
    bsum += __shfl_xor(bsum, off, 64);
  }
  float mu = s1 * (1.f / 64.f);
  float var = s2 * (1.f / 64.f) - mu * mu;
  float rstd = rsqrtf(var + 0.00064f);
  float z = (yv - mu) * rstd * gn_w[c] + gn_b[c];
  y[base] = f2bf((z + bsum * vv) * gv);
}

// ---------------------------------------------------------------- helpers
__global__ __launch_bounds__(256)
void copy_v0(const float* __restrict__ v0, float* __restrict__ out) {
  int idx = blockIdx.x * 256 + threadIdx.x;
  ((float4*)out)[idx] = ((const float4*)v0)[idx];
}

__global__ __launch_bounds__(256)
void zero_out(float* __restrict__ out) {
  int idx = blockIdx.x * 256 + threadIdx.x;
  ((float4*)out)[idx] = make_float4(0.f, 0.f, 0.f, 0.f);
}

// ----------------------------------------------------------------
extern "C" void kernel_launch(void* const* d_in, const int* in_sizes, int n_in,
                              void* d_out, int out_size, void* d_ws, size_t ws_size,
                              hipStream_t stream) {
  (void)n_in; (void)out_size;
  const bool dictOrder = (in_sizes[9] == CC);
  int IX[28];
  if (dictOrder) {
    const int m[28] = {0,1,2,3,4,5,6,7, 8,13,14, 9,15,16, 10,17,18, 19,20,
                       11,12,21, 22,23,24,25, 26,27};
    for (int i = 0; i < 28; ++i) IX[i] = m[i];
  } else {
    for (int i = 0; i < 28; ++i) IX[i] = i;
  }
  const float* x     = (const float*)d_in[IX[0]];
  const float* v0    = (const float*)d_in[IX[1]];
  const float* xx_r  = (const float*)d_in[IX[2]];
  const float* xx_w  = (const float*)d_in[IX[3]];
  const float* xx_k  = (const float*)d_in[IX[4]];
  const float* xx_v  = (const float*)d_in[IX[5]];
  const float* xx_a  = (const float*)d_in[IX[6]];
  const float* xx_g  = (const float*)d_in[IX[7]];
  const float* ww_b  = (const float*)d_in[IX[8]];
  const float* ww_w1 = (const float*)d_in[IX[9]];
  const float* ww_w2 = (const float*)d_in[IX[10]];
  const float* aa_b  = (const float*)d_in[IX[11]];
  const float* aa_w1 = (const float*)d_in[IX[12]];
  const float* aa_w2 = (const float*)d_in[IX[13]];
  const float* vv_b  = (const float*)d_in[IX[14]];
  const float* vv_w1 = (const float*)d_in[IX[15]];
  const float* vv_w2 = (const float*)d_in[IX[16]];
  const float* gg_w1 = (const float*)d_in[IX[17]];
  const float* gg_w2 = (const float*)d_in[IX[18]];
  const float* kk_s  = (const float*)d_in[IX[19]];
  const float* ka_s  = (const float*)d_in[IX[20]];
  const float* rk_s  = (const float*)d_in[IX[21]];
  const float* W_r   = (const float*)d_in[IX[22]];
  const float* W_k   = (const float*)d_in[IX[23]];
  const float* W_v   = (const float*)d_in[IX[24]];
  const float* W_o   = (const float*)d_in[IX[25]];
  const float* gn_w  = (const float*)d_in[IX[26]];
  const float* gn_b  = (const float*)d_in[IX[27]];

  const size_t NBTC = (size_t)BT * CC;      // 8,388,608 elements (16 MiB bf16)
  dim3 blk(256);
  const int grid4f = (int)(NBTC / 4 / 256);

  const size_t WS_NEED = 7 * NBTC * sizeof(u16);   // 112 MiB
  float* outF = (float*)d_out;
  if (ws_size < WS_NEED || d_ws == nullptr) {
    zero_out<<<grid4f, blk, 0, stream>>>(outF);
    copy_v0<<<grid4f, blk, 0, stream>>>(v0, outF + NBTC);
    return;
  }

  // Regions (16 MiB each): R0=h1/r  R1=Wt(early)/k  R2=v  R3=partY/Wt/kk/h2
  // R4=a/g  R5=w_raw -> partG/Wt(g,o)  R6=mix staging. y in d_out v0-slot.
  u16* W16   = (u16*)d_ws;
  u16* R0 = W16 + 0 * NBTC;
  u16* R1 = W16 + 1 * NBTC;
  u16* R2 = W16 + 2 * NBTC;
  u16* R3 = W16 + 3 * NBTC;
  u16* R4 = W16 + 4 * NBTC;
  u16* R5 = W16 + 5 * NBTC;
  u16* R6 = W16 + 6 * NBTC;
  float* partY = (float*)R3;      // <= 16 MiB, fits R3
  float* partG = (float*)R5;      // 8 MiB, fits R5
  u16* ws_y = (u16*)(outF + NBTC);

  const int gridMix = (BT * CC) / 256;      // 32768
  dim3 gM(BT / 128, 2048 / 128);            // (32, 16)

  // ---- w path
  mix_k<<<gridMix, blk, 0, stream>>>(x, xx_w, R6);
  gemm_part_k<<<dim3(32, 2, 8), blk, 0, stream>>>(R6, ww_w1, partY,
      BT, 96, 2048, 256, 128);
  reduce_k<<<(BT * 96 + 255) / 256, blk, 0, stream>>>(partY, R0, BT, 96, 128, 8, 1);
  wt_k<<<dim3(3, 64), blk, 0, stream>>>(ww_w2, R1, 96, 2048);
  mgemm_k<EPI_BIAS_SP><<<gM, blk, 0, stream>>>(R0, R1, nullptr, R5,
      BT, 2048, 96, ww_b, nullptr, nullptr);

  // ---- a path
  mix_k<<<gridMix, blk, 0, stream>>>(x, xx_a, R6);
  gemm_part_k<<<dim3(32, 2, 8), blk, 0, stream>>>(R6, aa_w1, partY,
      BT, 96, 2048, 256, 128);
  reduce_k<<<(BT * 96 + 255) / 256, blk, 0, stream>>>(partY, R0, BT, 96, 128, 8, 0);
  wt_k<<<dim3(3, 64), blk, 0, stream>>>(aa_w2, R1, 96, 2048);
  mgemm_k<EPI_BIAS_SIG><<<gM, blk, 0, stream>>>(R0, R1, nullptr, R4,
      BT, 2048, 96, aa_b, nullptr, nullptr);

  // ---- v path
  mix_k<<<gridMix, blk, 0, stream>>>(x, xx_v, R6);
  wt_k<<<dim3(64, 64), blk, 0, stream>>>(W_v, R1, 2048, 2048);
  mgemm_k<EPI_BF><<<gM, blk, 0, stream>>>(R6, R1, nullptr, R2,
      BT, 2048, 2048, nullptr, nullptr, nullptr);
  gemm_part_k<<<dim3(32, 1, 8), blk, 0, stream>>>(R6, vv_w1, partY,
      BT, 64, 2048, 256, 64);
  reduce_k<<<(BT * 64 + 255) / 256, blk, 0, stream>>>(partY, R0, BT, 64, 64, 8, 0);
  wt_k<<<dim3(2, 64), blk, 0, stream>>>(vv_w2, R1, 64, 2048);
  mgemm_k<EPI_VMIX><<<gM, blk, 0, stream>>>(R0, R1, nullptr, R2,
      BT, 2048, 64, vv_b, R2, v0);

  // ---- k path
  mix_k<<<gridMix, blk, 0, stream>>>(x, xx_k, R6);
  wt_k<<<dim3(64, 64), blk, 0, stream>>>(W_k, R3, 2048, 2048);
  mgemm_k<EPI_BF><<<gM, blk, 0, stream>>>(R6, R3, nullptr, R1,
      BT, 2048, 2048, nullptr, nullptr, nullptr);

  // ---- r path
  mix_k<<<gridMix, blk, 0, stream>>>(x, xx_r, R6);
  wt_k<<<dim3(64, 64), blk, 0, stream>>>(W_r, R3, 2048, 2048);
  mgemm_k<EPI_BF><<<gM, blk, 0, stream>>>(R6, R3, nullptr, R0,
      BT, 2048, 2048, nullptr, nullptr, nullptr);

  // ---- kk / k-final (R3's Wt_r dead)
  kkprep_k<<<BT * HH / 4, blk, 0, stream>>>(R1, R4, kk_s, ka_s, R3, R1);

  // ---- recurrence: r=R0 w=R5 k=R1 v=R2 kk=R3 a=R4 -> y
  rec_k<<<(BB * HH * 64) / 4, blk, 0, stream>>>(R0, R5, R1, R2, R3, R4, ws_y);

  // ---- g path (R5, R3, R4 dead after rec)
  mix_k<<<gridMix, blk, 0, stream>>>(x, xx_g, R6);
  gemm_part_k<<<dim3(32, 4, 2), blk, 0, stream>>>(R6, gg_w1, partG,
      BT, 256, 2048, 1024, 256);
  reduce_k<<<(BT * 256 + 255) / 256, blk, 0, stream>>>(partG, R3, BT, 256, 256, 2, 2);
  wt_k<<<dim3(8, 64), blk, 0, stream>>>(gg_w2, R5, 256, 2048);
  mgemm_k<EPI_BF><<<gM, blk, 0, stream>>>(R3, R5, nullptr, R4,
      BT, 2048, 256, nullptr, nullptr, nullptr);

  // ---- groupnorm + bonus + gate (in place on y)
  gn_k<<<BT * HH / 4, blk, 0, stream>>>(ws_y, R0, R1, R2, R4,
                                        rk_s, gn_w, gn_b);

  // ---- final projection y @ W_o -> fp32 output 0
  wt_k<<<dim3(64, 64), blk, 0, stream>>>(W_o, R5, 2048, 2048);
  mgemm_k<EPI_F32><<<gM, blk, 0, stream>>>(ws_y, R5, outF, nullptr,
      BT, 2048, 2048, nullptr, nullptr, nullptr);

  // ---- v0 passthrough (overwrites y scratch slot, last)
  copy_v0<<<grid4f, blk, 0, stream>>>(v0, outF + NBTC);
}

// Round 8
// 1152.283 us; speedup vs baseline: 2.0344x; 1.0289x over previous
//
#include <hip/hip_runtime.h>
#include <hip/hip_bf16.h>
#include <math.h>

typedef unsigned short u16;
typedef __attribute__((ext_vector_type(8))) unsigned short us8;
typedef __attribute__((ext_vector_type(8))) short s8v;   // mfma bf16 operand (4 VGPRs)
typedef __attribute__((ext_vector_type(4))) float f4v;   // mfma accum

#define BB 2
#define TT 1024
#define CC 2048
#define HH 32
#define BT (BB*TT)

// Inputs/outputs fp32. ws intermediates bf16: 7 regions x NBTC u16 = 112 MiB
// (ws_size >= that, established rounds 4/5/7). Weights cvt-transposed to bf16
// [N][K] just-in-time into dead regions for the MFMA GEMMs. Recurrence scalars
// (kr, br per (b,t,h)) live in the back half of d_out's v0 slot until copy_v0.

__device__ __forceinline__ float bf2f(u16 u) {
  return __uint_as_float(((unsigned int)u) << 16);
}
__device__ __forceinline__ u16 f2bf(float f) {
  unsigned int x = __float_as_uint(f);
  x += 0x7fffu + ((x >> 16) & 1u);
  return (u16)(x >> 16);
}

// ---------------------------------------------------------------- mix kernel
__global__ __launch_bounds__(256)
void mix_k(const float* __restrict__ x, const float* __restrict__ s,
           u16* __restrict__ out) {
  int idx = blockIdx.x * 256 + threadIdx.x;       // over BT*C
  int c = idx & (CC - 1);
  int t = (idx >> 11) & (TT - 1);
  float xv = x[idx];
  float xp = (t == 0) ? 0.f : x[idx - CC];
  out[idx] = f2bf(xv + (xp - xv) * s[c]);
}

// ---------------------------------------------------------------- weight cvt-transpose
// W fp32 [K][N] -> Wt bf16 [N][K]. 32x32 tiles, 256 threads.
__global__ __launch_bounds__(256)
void wt_k(const float* __restrict__ W, u16* __restrict__ Wt, int K, int N) {
  __shared__ u16 tile[32][36];
  const int k0 = blockIdx.x * 32, n0 = blockIdx.y * 32;
  const int tid = threadIdx.x;
  const int r = tid >> 3, c4 = (tid & 7) << 2;
  float4 v = *(const float4*)(W + (size_t)(k0 + r) * N + n0 + c4);
  tile[r][c4 + 0] = f2bf(v.x); tile[r][c4 + 1] = f2bf(v.y);
  tile[r][c4 + 2] = f2bf(v.z); tile[r][c4 + 3] = f2bf(v.w);
  __syncthreads();
  ushort4 o;
  o.x = tile[c4 + 0][r]; o.y = tile[c4 + 1][r];
  o.z = tile[c4 + 2][r]; o.w = tile[c4 + 3][r];
  *(ushort4*)(Wt + (size_t)(n0 + r) * K + k0 + c4) = o;
}

// ---------------------------------------------------------------- MFMA GEMM
// C[M,N] = A[M,K](bf16, pitch K) * B(given as Bt[N][K] bf16), fp32 accum.
// Block tile 128x128, BK=32, 4 waves (2x2), wave tile 64x64 = 4x4 frags.
enum { EPI_BF = 0, EPI_F32 = 1, EPI_BIAS_SP = 2, EPI_BIAS_SIG = 3,
       EPI_VMIX = 4 };

template<int EPI>
__global__ __launch_bounds__(256)
void mgemm_k(const u16* __restrict__ A, const u16* __restrict__ Bt,
             float* __restrict__ outF, u16* __restrict__ outB,
             int M, int N, int K,
             const float* __restrict__ bias, const u16* __restrict__ p1,
             const float* __restrict__ p2)
{
  __shared__ alignas(16) u16 As[128][40];   // 32 k + 8 pad (80 B row stride)
  __shared__ alignas(16) u16 Bs[128][40];
  const int m0 = blockIdx.x * 128;
  const int n0 = blockIdx.y * 128;
  const int tid = threadIdx.x;
  const int lane = tid & 63;
  const int wid = tid >> 6;
  const int wr = wid >> 1, wc = wid & 1;        // wave quadrant (2x2)
  const int srow = tid >> 1;                    // staging row (0..127)
  const int scol = (tid & 1) << 4;              // staging k-col (0 or 16)
  f4v acc[4][4];
  #pragma unroll
  for (int i = 0; i < 4; ++i)
    #pragma unroll
    for (int j = 0; j < 4; ++j) acc[i][j] = f4v{0.f, 0.f, 0.f, 0.f};

  const int l15 = lane & 15;
  const int lk = (lane >> 4) << 3;              // k offset within BK (0,8,16,24)
  const int nkt = K >> 5;
  for (int kt = 0; kt < nkt; ++kt) {
    const int k0 = kt << 5;
    const u16* ap = A  + (size_t)(m0 + srow) * K + k0 + scol;
    const u16* bp = Bt + (size_t)(n0 + srow) * K + k0 + scol;
    us8 a0 = *(const us8*)(ap);
    us8 a1 = *(const us8*)(ap + 8);
    us8 b0 = *(const us8*)(bp);
    us8 b1 = *(const us8*)(bp + 8);
    __syncthreads();                            // prev compute done
    *(us8*)&As[srow][scol]     = a0;
    *(us8*)&As[srow][scol + 8] = a1;
    *(us8*)&Bs[srow][scol]     = b0;
    *(us8*)&Bs[srow][scol + 8] = b1;
    __syncthreads();
    s8v af[4], bfr[4];
    #pragma unroll
    for (int i = 0; i < 4; ++i)
      af[i] = *(const s8v*)&As[wr * 64 + i * 16 + l15][lk];
    #pragma unroll
    for (int j = 0; j < 4; ++j)
      bfr[j] = *(const s8v*)&Bs[wc * 64 + j * 16 + l15][lk];
    #pragma unroll
    for (int i = 0; i < 4; ++i)
      #pragma unroll
      for (int j = 0; j < 4; ++j)
        acc[i][j] = __builtin_amdgcn_mfma_f32_16x16x32_bf16(af[i], bfr[j],
                                                            acc[i][j], 0, 0, 0);
  }
  // C/D layout: col = lane&15, row = (lane>>4)*4 + q  (m89-verified)
  const int rbase = m0 + wr * 64 + ((lane >> 4) << 2);
  const int cbase = n0 + wc * 64 + l15;
  #pragma unroll
  for (int i = 0; i < 4; ++i) {
    #pragma unroll
    for (int j = 0; j < 4; ++j) {
      f4v c = acc[i][j];
      const int col = cbase + j * 16;
      #pragma unroll
      for (int q = 0; q < 4; ++q) {
        const int row = rbase + i * 16 + q;
        const size_t idx = (size_t)row * N + col;
        const float r = c[q];
        if (EPI == EPI_BF) {
          outB[idx] = f2bf(r);
        } else if (EPI == EPI_F32) {
          outF[idx] = r;
        } else if (EPI == EPI_BIAS_SP) {
          float u = bias[col] + r;
          float z = -u;
          float sp = fmaxf(z, 0.f) + log1pf(expf(-fabsf(z)));
          outB[idx] = f2bf(-sp - 0.5f);
        } else if (EPI == EPI_BIAS_SIG) {
          float u = bias[col] + r;
          outB[idx] = f2bf(1.f / (1.f + expf(-u)));
        } else if (EPI == EPI_VMIX) {
          float u = bias[col] + r;
          float sg = 1.f / (1.f + expf(-u));
          float v = bf2f(p1[idx]);
          float v0v = p2[idx];
          outB[idx] = f2bf(v + (v0v - v) * sg);
        }
      }
    }
  }
}

// ---------------------------------------------------------------- SIMT GEMM (skinny w1 paths)
__global__ __launch_bounds__(256)
void gemm_part_k(const u16* __restrict__ A, const float* __restrict__ W,
                 float* __restrict__ outF, int M, int N, int K, int kchunk,
                 int NP)
{
  __shared__ alignas(16) float As[16][68];
  __shared__ alignas(16) float Bs[16][68];
  const int m0 = blockIdx.x * 64;
  const int n0 = blockIdx.y * 64;
  const int kz = blockIdx.z;
  const int k0base = kz * kchunk;
  const int tid = threadIdx.x;
  const int tx = tid & 15, ty = tid >> 4;
  float acc[4][4] = {{0.f}};
  const int a_m = tid >> 2;
  const int a_k = (tid & 3) << 2;
  const int b_k = tid >> 4;
  const int b_n = (tid & 15) << 2;
  const int niters = kchunk >> 4;
  for (int it = 0; it < niters; ++it) {
    const int k0 = k0base + (it << 4);
    float4 av;
    {
      ushort4 u = *(const ushort4*)(A + (size_t)(m0 + a_m) * K + (k0 + a_k));
      av = make_float4(bf2f(u.x), bf2f(u.y), bf2f(u.z), bf2f(u.w));
    }
    float4 bv;
    {
      int gn = n0 + b_n;
      const float* wp = W + (size_t)(k0 + b_k) * N + gn;
      if (gn + 3 < N) {
        bv = *(const float4*)wp;
      } else {
        bv.x = (gn + 0 < N) ? wp[0] : 0.f;
        bv.y = (gn + 1 < N) ? wp[1] : 0.f;
        bv.z = (gn + 2 < N) ? wp[2] : 0.f;
        bv.w = (gn + 3 < N) ? wp[3] : 0.f;
      }
    }
    __syncthreads();
    As[a_k + 0][a_m] = av.x; As[a_k + 1][a_m] = av.y;
    As[a_k + 2][a_m] = av.z; As[a_k + 3][a_m] = av.w;
    Bs[b_k][b_n + 0] = bv.x; Bs[b_k][b_n + 1] = bv.y;
    Bs[b_k][b_n + 2] = bv.z; Bs[b_k][b_n + 3] = bv.w;
    __syncthreads();
    #pragma unroll
    for (int kk = 0; kk < 16; ++kk) {
      float4 a4 = *(const float4*)&As[kk][ty << 2];
      float4 b4 = *(const float4*)&Bs[kk][tx << 2];
      float ar[4] = {a4.x, a4.y, a4.z, a4.w};
      float br[4] = {b4.x, b4.y, b4.z, b4.w};
      #pragma unroll
      for (int i = 0; i < 4; ++i)
        #pragma unroll
        for (int j = 0; j < 4; ++j)
          acc[i][j] = fmaf(ar[i], br[j], acc[i][j]);
    }
  }
  #pragma unroll
  for (int i = 0; i < 4; ++i) {
    int gm = m0 + (ty << 2) + i;
    #pragma unroll
    for (int j = 0; j < 4; ++j) {
      int gn = n0 + (tx << 2) + j;
      if (gn >= N) continue;
      outF[((size_t)kz * M + gm) * NP + gn] = acc[i][j];
    }
  }
}

// ---------------------------------------------------------------- K-split reduce
__global__ __launch_bounds__(256)
void reduce_k(const float* __restrict__ part, u16* __restrict__ out,
              int M, int D, int NP, int nz, int act)
{
  int idx = blockIdx.x * 256 + threadIdx.x;
  if (idx >= M * D) return;
  int t = idx / D, n = idx - t * D;
  float s = 0.f;
  for (int z = 0; z < nz; ++z) s += part[((size_t)z * M + t) * NP + n];
  if (act == 1) s = tanhf(s);
  else if (act == 2) s = 1.f / (1.f + expf(-s));
  out[idx] = f2bf(s);
}

// ---------------------------------------------------------------- recurrence prep
// Per (b,t,h) wave (lane = j): from k, a, r, w_raw compute
//   kkn = normalize(k*kk_s);  ao=-kkn;  bo=kkn*a;  kf=k*(1+(a-1)*ka_s);
//   wd = exp(-exp(w_raw));    rw = wd*r;
//   scalars kr = sum_j kf*r,  br = sum_j bo*r  (fp32, per (b,t,h))
__global__ __launch_bounds__(256)
void prep_k(const u16* __restrict__ k_in, const u16* __restrict__ a_in,
            const u16* __restrict__ r_in, const u16* __restrict__ w_in,
            const float* __restrict__ kk_s, const float* __restrict__ ka_s,
            u16* __restrict__ ao_out, u16* __restrict__ bo_out,
            u16* __restrict__ k_out, u16* __restrict__ wd_out,
            u16* __restrict__ rw_out, float* __restrict__ scal)
{
  int tid = threadIdx.x;
  int lane = tid & 63;
  int wv = tid >> 6;
  int hidx = blockIdx.x * 4 + wv;               // (b*T+t)*H + h
  int h = hidx & (HH - 1);
  int c = (h << 6) + lane;
  size_t base = ((size_t)hidx << 6) + lane;
  float k = bf2f(k_in[base]);
  float kk = k * kk_s[c];
  float ss = kk * kk;
  for (int off = 32; off; off >>= 1) ss += __shfl_xor(ss, off, 64);
  float kkn = kk / fmaxf(sqrtf(ss), 1e-12f);
  float a = bf2f(a_in[base]);
  float r = bf2f(r_in[base]);
  float kf = k * (1.f + (a - 1.f) * ka_s[c]);
  float wd = expf(-expf(bf2f(w_in[base])));
  float bo = kkn * a;
  ao_out[base] = f2bf(-kkn);
  bo_out[base] = f2bf(bo);
  k_out[base]  = f2bf(kf);
  wd_out[base] = f2bf(wd);
  rw_out[base] = f2bf(wd * r);
  float kr = kf * r, br = bo * r;
  kr += __shfl_xor(kr, 1, 64);  br += __shfl_xor(br, 1, 64);
  kr += __shfl_xor(kr, 2, 64);  br += __shfl_xor(br, 2, 64);
  kr += __shfl_xor(kr, 4, 64);  br += __shfl_xor(br, 4, 64);
  kr += __shfl_xor(kr, 8, 64);  br += __shfl_xor(br, 8, 64);
  kr += __shfl_xor(kr, 16, 64); br += __shfl_xor(br, 16, 64);
  kr += __shfl_xor(kr, 32, 64); br += __shfl_xor(br, 32, 64);
  if (lane == 0) {
    scal[hidx] = kr;
    scal[(size_t)BT * HH + hidx] = br;
  }
}

// ---------------------------------------------------------------- RWKV7 recurrence
// Wave-per-row (row i of head (b,h)); lane = j. Per step, the two
// state-dependent reductions (sa on ao, yw on rw) run as interleaved
// butterflies (chain 6 levels, ILP 2); the output uses precomputed
// scalars:  y[i] = yw + sa*br + v[i]*kr.
__global__ __launch_bounds__(256)
void rec_k(const u16* __restrict__ rw, const u16* __restrict__ wd,
           const u16* __restrict__ k, const u16* __restrict__ v,
           const u16* __restrict__ ao, const u16* __restrict__ bo,
           const float* __restrict__ scal, u16* __restrict__ y)
{
  const int gw = blockIdx.x * 4 + (threadIdx.x >> 6);
  const int lane = threadIdx.x & 63;
  const int bh = gw >> 6;
  const int i  = gw & 63;
  const int b = bh >> 5, h = bh & (HH - 1);
  const size_t base0 = ((size_t)b * TT) * CC + (h << 6);
  const size_t vecbase = base0 + lane;
  const size_t vbase   = base0 + i;
  const int sbase = b * TT * HH + h;           // + t*HH
  float s = 0.f;
  float pwd = bf2f(wd[vecbase]);
  float pk  = bf2f(k[vecbase]);
  float pao = bf2f(ao[vecbase]);
  float pbo = bf2f(bo[vecbase]);
  float prw = bf2f(rw[vecbase]);
  float pv  = bf2f(v[vbase]);
  float pkr = scal[sbase];
  float pbr = scal[(size_t)BT * HH + sbase];
  for (int t = 0; t < TT; ++t) {
    const float cwd = pwd, ck = pk, cao = pao, cbo = pbo, crw = prw,
                cv = pv, ckr = pkr, cbr = pbr;
    if (t + 1 < TT) {
      const size_t nb = vecbase + (size_t)(t + 1) * CC;
      pwd = bf2f(wd[nb]); pk = bf2f(k[nb]); pao = bf2f(ao[nb]);
      pbo = bf2f(bo[nb]); prw = bf2f(rw[nb]);
      pv = bf2f(v[vbase + (size_t)(t + 1) * CC]);
      pkr = scal[sbase + (t + 1) * HH];
      pbr = scal[(size_t)BT * HH + sbase + (t + 1) * HH];
    }
    float sa = s * cao;                         // -> sum_j S*ao
    float yw = s * crw;                         // -> sum_j S*wd*r
    sa += __shfl_xor(sa, 1, 64);  yw += __shfl_xor(yw, 1, 64);
    sa += __shfl_xor(sa, 2, 64);  yw += __shfl_xor(yw, 2, 64);
    sa += __shfl_xor(sa, 4, 64);  yw += __shfl_xor(yw, 4, 64);
    sa += __shfl_xor(sa, 8, 64);  yw += __shfl_xor(yw, 8, 64);
    sa += __shfl_xor(sa, 16, 64); yw += __shfl_xor(yw, 16, 64);
    sa += __shfl_xor(sa, 32, 64); yw += __shfl_xor(yw, 32, 64);
    s = fmaf(cv, ck, fmaf(sa, cbo, s * cwd));
    float o = fmaf(cv, ckr, fmaf(sa, cbr, yw));
    if (lane == 0) y[vbase + (size_t)t * CC] = f2bf(o);
  }
}

// ---------------------------------------------------------------- GroupNorm + bonus + gate
__global__ __launch_bounds__(256)
void gn_k(u16* __restrict__ y, const u16* __restrict__ r,
          const u16* __restrict__ k, const u16* __restrict__ v,
          const u16* __restrict__ g, const float* __restrict__ rk_s,
          const float* __restrict__ gn_w, const float* __restrict__ gn_b)
{
  int tid = threadIdx.x, lane = tid & 63, wv = tid >> 6;
  int hidx = blockIdx.x * 4 + wv;
  int h = hidx & (HH - 1);
  int c = (h << 6) + lane;
  size_t base = ((size_t)hidx << 6) + lane;
  float yv = bf2f(y[base]), rv = bf2f(r[base]), kv = bf2f(k[base]);
  float vv = bf2f(v[base]), gv = bf2f(g[base]);
  float bsum = rv * kv * rk_s[c];
  float s1 = yv, s2 = yv * yv;
  for (int off = 32; off; off >>= 1) {
    s1 += __shfl_xor(s1, off, 64);
    s2 += __shfl_xor(s2, off, 64);
    bsum += __shfl_xor(bsum, off, 64);
  }
  float mu = s1 * (1.f / 64.f);
  float var = s2 * (1.f / 64.f) - mu * mu;
  float rstd = rsqrtf(var + 0.00064f);
  float z = (yv - mu) * rstd * gn_w[c] + gn_b[c];
  y[base] = f2bf((z + bsum * vv) * gv);
}

// ---------------------------------------------------------------- helpers
__global__ __launch_bounds__(256)
void copy_v0(const float* __restrict__ v0, float* __restrict__ out) {
  int idx = blockIdx.x * 256 + threadIdx.x;
  ((float4*)out)[idx] = ((const float4*)v0)[idx];
}

__global__ __launch_bounds__(256)
void zero_out(float* __restrict__ out) {
  int idx = blockIdx.x * 256 + threadIdx.x;
  ((float4*)out)[idx] = make_float4(0.f, 0.f, 0.f, 0.f);
}

// ----------------------------------------------------------------
extern "C" void kernel_launch(void* const* d_in, const int* in_sizes, int n_in,
                              void* d_out, int out_size, void* d_ws, size_t ws_size,
                              hipStream_t stream) {
  (void)n_in; (void)out_size;
  const bool dictOrder = (in_sizes[9] == CC);
  int IX[28];
  if (dictOrder) {
    const int m[28] = {0,1,2,3,4,5,6,7, 8,13,14, 9,15,16, 10,17,18, 19,20,
                       11,12,21, 22,23,24,25, 26,27};
    for (int i = 0; i < 28; ++i) IX[i] = m[i];
  } else {
    for (int i = 0; i < 28; ++i) IX[i] = i;
  }
  const float* x     = (const float*)d_in[IX[0]];
  const float* v0    = (const float*)d_in[IX[1]];
  const float* xx_r  = (const float*)d_in[IX[2]];
  const float* xx_w  = (const float*)d_in[IX[3]];
  const float* xx_k  = (const float*)d_in[IX[4]];
  const float* xx_v  = (const float*)d_in[IX[5]];
  const float* xx_a  = (const float*)d_in[IX[6]];
  const float* xx_g  = (const float*)d_in[IX[7]];
  const float* ww_b  = (const float*)d_in[IX[8]];
  const float* ww_w1 = (const float*)d_in[IX[9]];
  const float* ww_w2 = (const float*)d_in[IX[10]];
  const float* aa_b  = (const float*)d_in[IX[11]];
  const float* aa_w1 = (const float*)d_in[IX[12]];
  const float* aa_w2 = (const float*)d_in[IX[13]];
  const float* vv_b  = (const float*)d_in[IX[14]];
  const float* vv_w1 = (const float*)d_in[IX[15]];
  const float* vv_w2 = (const float*)d_in[IX[16]];
  const float* gg_w1 = (const float*)d_in[IX[17]];
  const float* gg_w2 = (const float*)d_in[IX[18]];
  const float* kk_s  = (const float*)d_in[IX[19]];
  const float* ka_s  = (const float*)d_in[IX[20]];
  const float* rk_s  = (const float*)d_in[IX[21]];
  const float* W_r   = (const float*)d_in[IX[22]];
  const float* W_k   = (const float*)d_in[IX[23]];
  const float* W_v   = (const float*)d_in[IX[24]];
  const float* W_o   = (const float*)d_in[IX[25]];
  const float* gn_w  = (const float*)d_in[IX[26]];
  const float* gn_b  = (const float*)d_in[IX[27]];

  const size_t NBTC = (size_t)BT * CC;      // 8,388,608 elements (16 MiB bf16)
  dim3 blk(256);
  const int grid4f = (int)(NBTC / 4 / 256);

  const size_t WS_NEED = 7 * NBTC * sizeof(u16);   // 112 MiB
  float* outF = (float*)d_out;
  if (ws_size < WS_NEED || d_ws == nullptr) {
    zero_out<<<grid4f, blk, 0, stream>>>(outF);
    copy_v0<<<grid4f, blk, 0, stream>>>(v0, outF + NBTC);
    return;
  }

  // Regions (16 MiB each): R0=h1/r  R1=Wt(early)/k  R2=v  R3=partY/Wt/ao/h2
  // R4=a/bo/g  R5=w_raw/wd -> partG/Wt(g,o)  R6=mix staging/rw.
  // y (bf16) in d_out v0-slot front half; kr/br scalars in its back half.
  u16* W16   = (u16*)d_ws;
  u16* R0 = W16 + 0 * NBTC;
  u16* R1 = W16 + 1 * NBTC;
  u16* R2 = W16 + 2 * NBTC;
  u16* R3 = W16 + 3 * NBTC;
  u16* R4 = W16 + 4 * NBTC;
  u16* R5 = W16 + 5 * NBTC;
  u16* R6 = W16 + 6 * NBTC;
  float* partY = (float*)R3;      // <= 16 MiB, fits R3
  float* partG = (float*)R5;      // 8 MiB, fits R5
  u16* ws_y = (u16*)(outF + NBTC);          // bf16 y: front 16 MiB of v0 slot
  float* scal = (float*)(ws_y + NBTC);      // kr/br: 1 MiB in back half

  const int gridMix = (BT * CC) / 256;      // 32768
  dim3 gM(BT / 128, 2048 / 128);            // (32, 16)

  // ---- w path
  mix_k<<<gridMix, blk, 0, stream>>>(x, xx_w, R6);
  gemm_part_k<<<dim3(32, 2, 8), blk, 0, stream>>>(R6, ww_w1, partY,
      BT, 96, 2048, 256, 128);
  reduce_k<<<(BT * 96 + 255) / 256, blk, 0, stream>>>(partY, R0, BT, 96, 128, 8, 1);
  wt_k<<<dim3(3, 64), blk, 0, stream>>>(ww_w2, R1, 96, 2048);
  mgemm_k<EPI_BIAS_SP><<<gM, blk, 0, stream>>>(R0, R1, nullptr, R5,
      BT, 2048, 96, ww_b, nullptr, nullptr);

  // ---- a path
  mix_k<<<gridMix, blk, 0, stream>>>(x, xx_a, R6);
  gemm_part_k<<<dim3(32, 2, 8), blk, 0, stream>>>(R6, aa_w1, partY,
      BT, 96, 2048, 256, 128);
  reduce_k<<<(BT * 96 + 255) / 256, blk, 0, stream>>>(partY, R0, BT, 96, 128, 8, 0);
  wt_k<<<dim3(3, 64), blk, 0, stream>>>(aa_w2, R1, 96, 2048);
  mgemm_k<EPI_BIAS_SIG><<<gM, blk, 0, stream>>>(R0, R1, nullptr, R4,
      BT, 2048, 96, aa_b, nullptr, nullptr);

  // ---- v path
  mix_k<<<gridMix, blk, 0, stream>>>(x, xx_v, R6);
  wt_k<<<dim3(64, 64), blk, 0, stream>>>(W_v, R1, 2048, 2048);
  mgemm_k<EPI_BF><<<gM, blk, 0, stream>>>(R6, R1, nullptr, R2,
      BT, 2048, 2048, nullptr, nullptr, nullptr);
  gemm_part_k<<<dim3(32, 1, 8), blk, 0, stream>>>(R6, vv_w1, partY,
      BT, 64, 2048, 256, 64);
  reduce_k<<<(BT * 64 + 255) / 256, blk, 0, stream>>>(partY, R0, BT, 64, 64, 8, 0);
  wt_k<<<dim3(2, 64), blk, 0, stream>>>(vv_w2, R1, 64, 2048);
  mgemm_k<EPI_VMIX><<<gM, blk, 0, stream>>>(R0, R1, nullptr, R2,
      BT, 2048, 64, vv_b, R2, v0);

  // ---- k path
  mix_k<<<gridMix, blk, 0, stream>>>(x, xx_k, R6);
  wt_k<<<dim3(64, 64), blk, 0, stream>>>(W_k, R3, 2048, 2048);
  mgemm_k<EPI_BF><<<gM, blk, 0, stream>>>(R6, R3, nullptr, R1,
      BT, 2048, 2048, nullptr, nullptr, nullptr);

  // ---- r path
  mix_k<<<gridMix, blk, 0, stream>>>(x, xx_r, R6);
  wt_k<<<dim3(64, 64), blk, 0, stream>>>(W_r, R3, 2048, 2048);
  mgemm_k<EPI_BF><<<gM, blk, 0, stream>>>(R6, R3, nullptr, R0,
      BT, 2048, 2048, nullptr, nullptr, nullptr);

  // ---- recurrence prep: k(R1),a(R4),r(R0),w_raw(R5) ->
  //      ao(R3), bo(R4), kf(R1), wd(R5), rw(R6), scal
  prep_k<<<BT * HH / 4, blk, 0, stream>>>(R1, R4, R0, R5, kk_s, ka_s,
                                          R3, R4, R1, R5, R6, scal);

  // ---- recurrence: rw=R6 wd=R5 k=R1 v=R2 ao=R3 bo=R4 -> y
  rec_k<<<(BB * HH * 64) / 4, blk, 0, stream>>>(R6, R5, R1, R2, R3, R4,
                                                scal, ws_y);

  // ---- g path (R5, R3, R4, R6 dead after rec)
  mix_k<<<gridMix, blk, 0, stream>>>(x, xx_g, R6);
  gemm_part_k<<<dim3(32, 4, 2), blk, 0, stream>>>(R6, gg_w1, partG,
      BT, 256, 2048, 1024, 256);
  reduce_k<<<(BT * 256 + 255) / 256, blk, 0, stream>>>(partG, R3, BT, 256, 256, 2, 2);
  wt_k<<<dim3(8, 64), blk, 0, stream>>>(gg_w2, R5, 256, 2048);
  mgemm_k<EPI_BF><<<gM, blk, 0, stream>>>(R3, R5, nullptr, R4,
      BT, 2048, 256, nullptr, nullptr, nullptr);

  // ---- groupnorm + bonus + gate (in place on y)
  gn_k<<<BT * HH / 4, blk, 0, stream>>>(ws_y, R0, R1, R2, R4,
                                        rk_s, gn_w, gn_b);

  // ---- final projection y @ W_o -> fp32 output 0
  wt_k<<<dim3(64, 64), blk, 0, stream>>>(W_o, R5, 2048, 2048);
  mgemm_k<EPI_F32><<<gM, blk, 0, stream>>>(ws_y, R5, outF, nullptr,
      BT, 2048, 2048, nullptr, nullptr, nullptr);

  // ---- v0 passthrough (overwrites y scratch + scal, last)
  copy_v0<<<grid4f, blk, 0, stream>>>(v0, outF + NBTC);
}

// Round 9
// 980.484 us; speedup vs baseline: 2.3908x; 1.1752x over previous
//
#include <hip/hip_runtime.h>
#include <hip/hip_bf16.h>
#include <math.h>

typedef unsigned short u16;
typedef __attribute__((ext_vector_type(4))) unsigned short us4;
typedef __attribute__((ext_vector_type(8))) unsigned short us8;
typedef __attribute__((ext_vector_type(8))) short s8v;   // mfma bf16 operand (4 VGPRs)
typedef __attribute__((ext_vector_type(4))) float f4v;   // mfma accum

#define BB 2
#define TT 1024
#define CC 2048
#define HH 32
#define BT (BB*TT)

// Inputs/outputs fp32. ws intermediates bf16: 7 regions x NBTC u16 = 112 MiB
// (ws_size >= that, established rounds 4/5/7). Weights cvt-transposed to bf16
// [N][K] just-in-time into dead regions for the MFMA GEMMs. Recurrence scalars
// (kr, br per (b,t,h)) live in the back half of d_out's v0 slot until copy_v0.

__device__ __forceinline__ float bf2f(u16 u) {
  return __uint_as_float(((unsigned int)u) << 16);
}
__device__ __forceinline__ u16 f2bf(float f) {
  unsigned int x = __float_as_uint(f);
  x += 0x7fffu + ((x >> 16) & 1u);
  return (u16)(x >> 16);
}

// ---------------------------------------------------------------- mix kernel
__global__ __launch_bounds__(256)
void mix_k(const float* __restrict__ x, const float* __restrict__ s,
           u16* __restrict__ out) {
  int idx = blockIdx.x * 256 + threadIdx.x;       // over BT*C
  int c = idx & (CC - 1);
  int t = (idx >> 11) & (TT - 1);
  float xv = x[idx];
  float xp = (t == 0) ? 0.f : x[idx - CC];
  out[idx] = f2bf(xv + (xp - xv) * s[c]);
}

// ---------------------------------------------------------------- weight cvt-transpose
// W fp32 [K][N] -> Wt bf16 [N][K]. 32x32 tiles, 256 threads.
__global__ __launch_bounds__(256)
void wt_k(const float* __restrict__ W, u16* __restrict__ Wt, int K, int N) {
  __shared__ u16 tile[32][36];
  const int k0 = blockIdx.x * 32, n0 = blockIdx.y * 32;
  const int tid = threadIdx.x;
  const int r = tid >> 3, c4 = (tid & 7) << 2;
  float4 v = *(const float4*)(W + (size_t)(k0 + r) * N + n0 + c4);
  tile[r][c4 + 0] = f2bf(v.x); tile[r][c4 + 1] = f2bf(v.y);
  tile[r][c4 + 2] = f2bf(v.z); tile[r][c4 + 3] = f2bf(v.w);
  __syncthreads();
  ushort4 o;
  o.x = tile[c4 + 0][r]; o.y = tile[c4 + 1][r];
  o.z = tile[c4 + 2][r]; o.w = tile[c4 + 3][r];
  *(ushort4*)(Wt + (size_t)(n0 + r) * K + k0 + c4) = o;
}

// ---------------------------------------------------------------- MFMA GEMM
// C[M,N] = A[M,K](bf16, pitch K) * B(given as Bt[N][K] bf16), fp32 accum.
// Block tile 128x128, BK=32, 4 waves (2x2), wave tile 64x64 = 4x4 frags.
enum { EPI_BF = 0, EPI_F32 = 1, EPI_BIAS_SP = 2, EPI_BIAS_SIG = 3,
       EPI_VMIX = 4 };

template<int EPI>
__global__ __launch_bounds__(256)
void mgemm_k(const u16* __restrict__ A, const u16* __restrict__ Bt,
             float* __restrict__ outF, u16* __restrict__ outB,
             int M, int N, int K,
             const float* __restrict__ bias, const u16* __restrict__ p1,
             const float* __restrict__ p2)
{
  __shared__ alignas(16) u16 As[128][40];   // 32 k + 8 pad (80 B row stride)
  __shared__ alignas(16) u16 Bs[128][40];
  const int m0 = blockIdx.x * 128;
  const int n0 = blockIdx.y * 128;
  const int tid = threadIdx.x;
  const int lane = tid & 63;
  const int wid = tid >> 6;
  const int wr = wid >> 1, wc = wid & 1;        // wave quadrant (2x2)
  const int srow = tid >> 1;                    // staging row (0..127)
  const int scol = (tid & 1) << 4;              // staging k-col (0 or 16)
  f4v acc[4][4];
  #pragma unroll
  for (int i = 0; i < 4; ++i)
    #pragma unroll
    for (int j = 0; j < 4; ++j) acc[i][j] = f4v{0.f, 0.f, 0.f, 0.f};

  const int l15 = lane & 15;
  const int lk = (lane >> 4) << 3;              // k offset within BK (0,8,16,24)
  const int nkt = K >> 5;
  for (int kt = 0; kt < nkt; ++kt) {
    const int k0 = kt << 5;
    const u16* ap = A  + (size_t)(m0 + srow) * K + k0 + scol;
    const u16* bp = Bt + (size_t)(n0 + srow) * K + k0 + scol;
    us8 a0 = *(const us8*)(ap);
    us8 a1 = *(const us8*)(ap + 8);
    us8 b0 = *(const us8*)(bp);
    us8 b1 = *(const us8*)(bp + 8);
    __syncthreads();                            // prev compute done
    *(us8*)&As[srow][scol]     = a0;
    *(us8*)&As[srow][scol + 8] = a1;
    *(us8*)&Bs[srow][scol]     = b0;
    *(us8*)&Bs[srow][scol + 8] = b1;
    __syncthreads();
    s8v af[4], bfr[4];
    #pragma unroll
    for (int i = 0; i < 4; ++i)
      af[i] = *(const s8v*)&As[wr * 64 + i * 16 + l15][lk];
    #pragma unroll
    for (int j = 0; j < 4; ++j)
      bfr[j] = *(const s8v*)&Bs[wc * 64 + j * 16 + l15][lk];
    #pragma unroll
    for (int i = 0; i < 4; ++i)
      #pragma unroll
      for (int j = 0; j < 4; ++j)
        acc[i][j] = __builtin_amdgcn_mfma_f32_16x16x32_bf16(af[i], bfr[j],
                                                            acc[i][j], 0, 0, 0);
  }
  // C/D layout: col = lane&15, row = (lane>>4)*4 + q  (m89-verified)
  const int rbase = m0 + wr * 64 + ((lane >> 4) << 2);
  const int cbase = n0 + wc * 64 + l15;
  #pragma unroll
  for (int i = 0; i < 4; ++i) {
    #pragma unroll
    for (int j = 0; j < 4; ++j) {
      f4v c = acc[i][j];
      const int col = cbase + j * 16;
      #pragma unroll
      for (int q = 0; q < 4; ++q) {
        const int row = rbase + i * 16 + q;
        const size_t idx = (size_t)row * N + col;
        const float r = c[q];
        if (EPI == EPI_BF) {
          outB[idx] = f2bf(r);
        } else if (EPI == EPI_F32) {
          outF[idx] = r;
        } else if (EPI == EPI_BIAS_SP) {
          float u = bias[col] + r;
          float z = -u;
          float sp = fmaxf(z, 0.f) + log1pf(expf(-fabsf(z)));
          outB[idx] = f2bf(-sp - 0.5f);
        } else if (EPI == EPI_BIAS_SIG) {
          float u = bias[col] + r;
          outB[idx] = f2bf(1.f / (1.f + expf(-u)));
        } else if (EPI == EPI_VMIX) {
          float u = bias[col] + r;
          float sg = 1.f / (1.f + expf(-u));
          float v = bf2f(p1[idx]);
          float v0v = p2[idx];
          outB[idx] = f2bf(v + (v0v - v) * sg);
        }
      }
    }
  }
}

// ---------------------------------------------------------------- SIMT GEMM (skinny w1 paths)
__global__ __launch_bounds__(256)
void gemm_part_k(const u16* __restrict__ A, const float* __restrict__ W,
                 float* __restrict__ outF, int M, int N, int K, int kchunk,
                 int NP)
{
  __shared__ alignas(16) float As[16][68];
  __shared__ alignas(16) float Bs[16][68];
  const int m0 = blockIdx.x * 64;
  const int n0 = blockIdx.y * 64;
  const int kz = blockIdx.z;
  const int k0base = kz * kchunk;
  const int tid = threadIdx.x;
  const int tx = tid & 15, ty = tid >> 4;
  float acc[4][4] = {{0.f}};
  const int a_m = tid >> 2;
  const int a_k = (tid & 3) << 2;
  const int b_k = tid >> 4;
  const int b_n = (tid & 15) << 2;
  const int niters = kchunk >> 4;
  for (int it = 0; it < niters; ++it) {
    const int k0 = k0base + (it << 4);
    float4 av;
    {
      ushort4 u = *(const ushort4*)(A + (size_t)(m0 + a_m) * K + (k0 + a_k));
      av = make_float4(bf2f(u.x), bf2f(u.y), bf2f(u.z), bf2f(u.w));
    }
    float4 bv;
    {
      int gn = n0 + b_n;
      const float* wp = W + (size_t)(k0 + b_k) * N + gn;
      if (gn + 3 < N) {
        bv = *(const float4*)wp;
      } else {
        bv.x = (gn + 0 < N) ? wp[0] : 0.f;
        bv.y = (gn + 1 < N) ? wp[1] : 0.f;
        bv.z = (gn + 2 < N) ? wp[2] : 0.f;
        bv.w = (gn + 3 < N) ? wp[3] : 0.f;
      }
    }
    __syncthreads();
    As[a_k + 0][a_m] = av.x; As[a_k + 1][a_m] = av.y;
    As[a_k + 2][a_m] = av.z; As[a_k + 3][a_m] = av.w;
    Bs[b_k][b_n + 0] = bv.x; Bs[b_k][b_n + 1] = bv.y;
    Bs[b_k][b_n + 2] = bv.z; Bs[b_k][b_n + 3] = bv.w;
    __syncthreads();
    #pragma unroll
    for (int kk = 0; kk < 16; ++kk) {
      float4 a4 = *(const float4*)&As[kk][ty << 2];
      float4 b4 = *(const float4*)&Bs[kk][tx << 2];
      float ar[4] = {a4.x, a4.y, a4.z, a4.w};
      float br[4] = {b4.x, b4.y, b4.z, b4.w};
      #pragma unroll
      for (int i = 0; i < 4; ++i)
        #pragma unroll
        for (int j = 0; j < 4; ++j)
          acc[i][j] = fmaf(ar[i], br[j], acc[i][j]);
    }
  }
  #pragma unroll
  for (int i = 0; i < 4; ++i) {
    int gm = m0 + (ty << 2) + i;
    #pragma unroll
    for (int j = 0; j < 4; ++j) {
      int gn = n0 + (tx << 2) + j;
      if (gn >= N) continue;
      outF[((size_t)kz * M + gm) * NP + gn] = acc[i][j];
    }
  }
}

// ---------------------------------------------------------------- K-split reduce
__global__ __launch_bounds__(256)
void reduce_k(const float* __restrict__ part, u16* __restrict__ out,
              int M, int D, int NP, int nz, int act)
{
  int idx = blockIdx.x * 256 + threadIdx.x;
  if (idx >= M * D) return;
  int t = idx / D, n = idx - t * D;
  float s = 0.f;
  for (int z = 0; z < nz; ++z) s += part[((size_t)z * M + t) * NP + n];
  if (act == 1) s = tanhf(s);
  else if (act == 2) s = 1.f / (1.f + expf(-s));
  out[idx] = f2bf(s);
}

// ---------------------------------------------------------------- recurrence prep
// Per (b,t,h) wave (lane = j): from k, a, r, w_raw compute
//   kkn = normalize(k*kk_s);  ao=-kkn;  bo=kkn*a;  kf=k*(1+(a-1)*ka_s);
//   wd = exp(-exp(w_raw));    rw = wd*r;
//   scalars kr = sum_j kf*r,  br = sum_j bo*r  (fp32, per (b,t,h))
__global__ __launch_bounds__(256)
void prep_k(const u16* __restrict__ k_in, const u16* __restrict__ a_in,
            const u16* __restrict__ r_in, const u16* __restrict__ w_in,
            const float* __restrict__ kk_s, const float* __restrict__ ka_s,
            u16* __restrict__ ao_out, u16* __restrict__ bo_out,
            u16* __restrict__ k_out, u16* __restrict__ wd_out,
            u16* __restrict__ rw_out, float* __restrict__ scal)
{
  int tid = threadIdx.x;
  int lane = tid & 63;
  int wv = tid >> 6;
  int hidx = blockIdx.x * 4 + wv;               // (b*T+t)*H + h
  int h = hidx & (HH - 1);
  int c = (h << 6) + lane;
  size_t base = ((size_t)hidx << 6) + lane;
  float k = bf2f(k_in[base]);
  float kk = k * kk_s[c];
  float ss = kk * kk;
  for (int off = 32; off; off >>= 1) ss += __shfl_xor(ss, off, 64);
  float kkn = kk / fmaxf(sqrtf(ss), 1e-12f);
  float a = bf2f(a_in[base]);
  float r = bf2f(r_in[base]);
  float kf = k * (1.f + (a - 1.f) * ka_s[c]);
  float wd = expf(-expf(bf2f(w_in[base])));
  float bo = kkn * a;
  ao_out[base] = f2bf(-kkn);
  bo_out[base] = f2bf(bo);
  k_out[base]  = f2bf(kf);
  wd_out[base] = f2bf(wd);
  rw_out[base] = f2bf(wd * r);
  float kr = kf * r, br = bo * r;
  kr += __shfl_xor(kr, 1, 64);  br += __shfl_xor(br, 1, 64);
  kr += __shfl_xor(kr, 2, 64);  br += __shfl_xor(br, 2, 64);
  kr += __shfl_xor(kr, 4, 64);  br += __shfl_xor(br, 4, 64);
  kr += __shfl_xor(kr, 8, 64);  br += __shfl_xor(br, 8, 64);
  kr += __shfl_xor(kr, 16, 64); br += __shfl_xor(br, 16, 64);
  kr += __shfl_xor(kr, 32, 64); br += __shfl_xor(br, 32, 64);
  if (lane == 0) {
    scal[hidx] = kr;
    scal[(size_t)BT * HH + hidx] = br;
  }
}

// ---------------------------------------------------------------- RWKV7 recurrence
// g=16 geometry: each row i gets a 16-lane group; each lane holds 4 state
// elements (j = sub*4..sub*4+3). One wave = 4 rows of one head. Per step:
// 4 lane-local FMAs per reduction + 4 butterfly levels (masks 1,2,4,8)
// serving all 4 rows at once -> 8 ds-ops/step/wave (2 per row, was 12).
// y[i] = yw + sa*br + v[i]*kr on the pre-update state (round-8 identity).
__global__ __launch_bounds__(256)
void rec_k(const u16* __restrict__ rw, const u16* __restrict__ wd,
           const u16* __restrict__ kv, const u16* __restrict__ v,
           const u16* __restrict__ ao, const u16* __restrict__ bo,
           const float* __restrict__ scal, u16* __restrict__ y)
{
  const int gw = blockIdx.x * 4 + (threadIdx.x >> 6);   // 0..1023
  const int lane = threadIdx.x & 63;
  const int sub = lane & 15;                    // j-subgroup within row
  const int grp = lane >> 4;                    // row within wave's 4-row block
  const int bh = gw >> 4;                       // 0..63
  const int rblk = gw & 15;
  const int i = rblk * 4 + grp;                 // value-dim row
  const int b = bh >> 5, h = bh & (HH - 1);
  const size_t base0 = ((size_t)b * TT) * CC + (h << 6);
  const size_t vecb = base0 + (sub << 2);       // j-vector base (us4)
  const size_t vb   = base0 + i;                // v, y
  const int sbase = b * TT * HH + h;            // + t*HH
  float s0 = 0.f, s1 = 0.f, s2 = 0.f, s3 = 0.f;
  us4 pwd = *(const us4*)(wd + vecb);
  us4 pk  = *(const us4*)(kv + vecb);
  us4 pao = *(const us4*)(ao + vecb);
  us4 pbo = *(const us4*)(bo + vecb);
  us4 prw = *(const us4*)(rw + vecb);
  float pv  = bf2f(v[vb]);
  float pkr = scal[sbase];
  float pbr = scal[(size_t)BT * HH + sbase];
  for (int t = 0; t < TT; ++t) {
    const float w0 = bf2f(pwd[0]), w1 = bf2f(pwd[1]),
                w2 = bf2f(pwd[2]), w3 = bf2f(pwd[3]);
    const float q0 = bf2f(pk[0]),  q1 = bf2f(pk[1]),
                q2 = bf2f(pk[2]),  q3 = bf2f(pk[3]);
    const float a0 = bf2f(pao[0]), a1 = bf2f(pao[1]),
                a2 = bf2f(pao[2]), a3 = bf2f(pao[3]);
    const float c0 = bf2f(pbo[0]), c1 = bf2f(pbo[1]),
                c2 = bf2f(pbo[2]), c3 = bf2f(pbo[3]);
    const float e0 = bf2f(prw[0]), e1 = bf2f(prw[1]),
                e2 = bf2f(prw[2]), e3 = bf2f(prw[3]);
    const float cv = pv, ckr = pkr, cbr = pbr;
    if (t + 1 < TT) {
      const size_t nb = vecb + (size_t)(t + 1) * CC;
      pwd = *(const us4*)(wd + nb);
      pk  = *(const us4*)(kv + nb);
      pao = *(const us4*)(ao + nb);
      pbo = *(const us4*)(bo + nb);
      prw = *(const us4*)(rw + nb);
      pv  = bf2f(v[vb + (size_t)(t + 1) * CC]);
      pkr = scal[sbase + (t + 1) * HH];
      pbr = scal[(size_t)BT * HH + sbase + (t + 1) * HH];
    }
    float sa = fmaf(s3, a3, fmaf(s2, a2, fmaf(s1, a1, s0 * a0)));
    float yw = fmaf(s3, e3, fmaf(s2, e2, fmaf(s1, e1, s0 * e0)));
    sa += __shfl_xor(sa, 1, 64);  yw += __shfl_xor(yw, 1, 64);
    sa += __shfl_xor(sa, 2, 64);  yw += __shfl_xor(yw, 2, 64);
    sa += __shfl_xor(sa, 4, 64);  yw += __shfl_xor(yw, 4, 64);
    sa += __shfl_xor(sa, 8, 64);  yw += __shfl_xor(yw, 8, 64);
    s0 = fmaf(cv, q0, fmaf(sa, c0, s0 * w0));
    s1 = fmaf(cv, q1, fmaf(sa, c1, s1 * w1));
    s2 = fmaf(cv, q2, fmaf(sa, c2, s2 * w2));
    s3 = fmaf(cv, q3, fmaf(sa, c3, s3 * w3));
    float o = fmaf(cv, ckr, fmaf(sa, cbr, yw));
    if (sub == 0) y[vb + (size_t)t * CC] = f2bf(o);
  }
}

// ---------------------------------------------------------------- GroupNorm + bonus + gate
__global__ __launch_bounds__(256)
void gn_k(u16* __restrict__ y, const u16* __restrict__ r,
          const u16* __restrict__ k, const u16* __restrict__ v,
          const u16* __restrict__ g, const float* __restrict__ rk_s,
          const float* __restrict__ gn_w, const float* __restrict__ gn_b)
{
  int tid = threadIdx.x, lane = tid & 63, wv = tid >> 6;
  int hidx = blockIdx.x * 4 + wv;
  int h = hidx & (HH - 1);
  int c = (h << 6) + lane;
  size_t base = ((size_t)hidx << 6) + lane;
  float yv = bf2f(y[base]), rv = bf2f(r[base]), kv = bf2f(k[base]);
  float vv = bf2f(v[base]), gv = bf2f(g[base]);
  float bsum = rv * kv * rk_s[c];
  float s1 = yv, s2 = yv * yv;
  for (int off = 32; off; off >>= 1) {
    s1 += __shfl_xor(s1, off, 64);
    s2 += __shfl_xor(s2, off, 64);
    bsum += __shfl_xor(bsum, off, 64);
  }
  float mu = s1 * (1.f / 64.f);
  float var = s2 * (1.f / 64.f) - mu * mu;
  float rstd = rsqrtf(var + 0.00064f);
  float z = (yv - mu) * rstd * gn_w[c] + gn_b[c];
  y[base] = f2bf((z + bsum * vv) * gv);
}

// ---------------------------------------------------------------- helpers
__global__ __launch_bounds__(256)
void copy_v0(const float* __restrict__ v0, float* __restrict__ out) {
  int idx = blockIdx.x * 256 + threadIdx.x;
  ((float4*)out)[idx] = ((const float4*)v0)[idx];
}

__global__ __launch_bounds__(256)
void zero_out(float* __restrict__ out) {
  int idx = blockIdx.x * 256 + threadIdx.x;
  ((float4*)out)[idx] = make_float4(0.f, 0.f, 0.f, 0.f);
}

// ----------------------------------------------------------------
extern "C" void kernel_launch(void* const* d_in, const int* in_sizes, int n_in,
                              void* d_out, int out_size, void* d_ws, size_t ws_size,
                              hipStream_t stream) {
  (void)n_in; (void)out_size;
  const bool dictOrder = (in_sizes[9] == CC);
  int IX[28];
  if (dictOrder) {
    const int m[28] = {0,1,2,3,4,5,6,7, 8,13,14, 9,15,16, 10,17,18, 19,20,
                       11,12,21, 22,23,24,25, 26,27};
    for (int i = 0; i < 28; ++i) IX[i] = m[i];
  } else {
    for (int i = 0; i < 28; ++i) IX[i] = i;
  }
  const float* x     = (const float*)d_in[IX[0]];
  const float* v0    = (const float*)d_in[IX[1]];
  const float* xx_r  = (const float*)d_in[IX[2]];
  const float* xx_w  = (const float*)d_in[IX[3]];
  const float* xx_k  = (const float*)d_in[IX[4]];
  const float* xx_v  = (const float*)d_in[IX[5]];
  const float* xx_a  = (const float*)d_in[IX[6]];
  const float* xx_g  = (const float*)d_in[IX[7]];
  const float* ww_b  = (const float*)d_in[IX[8]];
  const float* ww_w1 = (const float*)d_in[IX[9]];
  const float* ww_w2 = (const float*)d_in[IX[10]];
  const float* aa_b  = (const float*)d_in[IX[11]];
  const float* aa_w1 = (const float*)d_in[IX[12]];
  const float* aa_w2 = (const float*)d_in[IX[13]];
  const float* vv_b  = (const float*)d_in[IX[14]];
  const float* vv_w1 = (const float*)d_in[IX[15]];
  const float* vv_w2 = (const float*)d_in[IX[16]];
  const float* gg_w1 = (const float*)d_in[IX[17]];
  const float* gg_w2 = (const float*)d_in[IX[18]];
  const float* kk_s  = (const float*)d_in[IX[19]];
  const float* ka_s  = (const float*)d_in[IX[20]];
  const float* rk_s  = (const float*)d_in[IX[21]];
  const float* W_r   = (const float*)d_in[IX[22]];
  const float* W_k   = (const float*)d_in[IX[23]];
  const float* W_v   = (const float*)d_in[IX[24]];
  const float* W_o   = (const float*)d_in[IX[25]];
  const float* gn_w  = (const float*)d_in[IX[26]];
  const float* gn_b  = (const float*)d_in[IX[27]];

  const size_t NBTC = (size_t)BT * CC;      // 8,388,608 elements (16 MiB bf16)
  dim3 blk(256);
  const int grid4f = (int)(NBTC / 4 / 256);

  const size_t WS_NEED = 7 * NBTC * sizeof(u16);   // 112 MiB
  float* outF = (float*)d_out;
  if (ws_size < WS_NEED || d_ws == nullptr) {
    zero_out<<<grid4f, blk, 0, stream>>>(outF);
    copy_v0<<<grid4f, blk, 0, stream>>>(v0, outF + NBTC);
    return;
  }

  // Regions (16 MiB each): R0=h1/r  R1=Wt(early)/k  R2=v  R3=partY/Wt/ao/h2
  // R4=a/bo/g  R5=w_raw/wd -> partG/Wt(g,o)  R6=mix staging/rw.
  // y (bf16) in d_out v0-slot front half; kr/br scalars in its back half.
  u16* W16   = (u16*)d_ws;
  u16* R0 = W16 + 0 * NBTC;
  u16* R1 = W16 + 1 * NBTC;
  u16* R2 = W16 + 2 * NBTC;
  u16* R3 = W16 + 3 * NBTC;
  u16* R4 = W16 + 4 * NBTC;
  u16* R5 = W16 + 5 * NBTC;
  u16* R6 = W16 + 6 * NBTC;
  float* partY = (float*)R3;      // <= 16 MiB, fits R3
  float* partG = (float*)R5;      // 8 MiB, fits R5
  u16* ws_y = (u16*)(outF + NBTC);          // bf16 y: front 16 MiB of v0 slot
  float* scal = (float*)(ws_y + NBTC);      // kr/br: 1 MiB in back half

  const int gridMix = (BT * CC) / 256;      // 32768
  dim3 gM(BT / 128, 2048 / 128);            // (32, 16)

  // ---- w path
  mix_k<<<gridMix, blk, 0, stream>>>(x, xx_w, R6);
  gemm_part_k<<<dim3(32, 2, 8), blk, 0, stream>>>(R6, ww_w1, partY,
      BT, 96, 2048, 256, 128);
  reduce_k<<<(BT * 96 + 255) / 256, blk, 0, stream>>>(partY, R0, BT, 96, 128, 8, 1);
  wt_k<<<dim3(3, 64), blk, 0, stream>>>(ww_w2, R1, 96, 2048);
  mgemm_k<EPI_BIAS_SP><<<gM, blk, 0, stream>>>(R0, R1, nullptr, R5,
      BT, 2048, 96, ww_b, nullptr, nullptr);

  // ---- a path
  mix_k<<<gridMix, blk, 0, stream>>>(x, xx_a, R6);
  gemm_part_k<<<dim3(32, 2, 8), blk, 0, stream>>>(R6, aa_w1, partY,
      BT, 96, 2048, 256, 128);
  reduce_k<<<(BT * 96 + 255) / 256, blk, 0, stream>>>(partY, R0, BT, 96, 128, 8, 0);
  wt_k<<<dim3(3, 64), blk, 0, stream>>>(aa_w2, R1, 96, 2048);
  mgemm_k<EPI_BIAS_SIG><<<gM, blk, 0, stream>>>(R0, R1, nullptr, R4,
      BT, 2048, 96, aa_b, nullptr, nullptr);

  // ---- v path
  mix_k<<<gridMix, blk, 0, stream>>>(x, xx_v, R6);
  wt_k<<<dim3(64, 64), blk, 0, stream>>>(W_v, R1, 2048, 2048);
  mgemm_k<EPI_BF><<<gM, blk, 0, stream>>>(R6, R1, nullptr, R2,
      BT, 2048, 2048, nullptr, nullptr, nullptr);
  gemm_part_k<<<dim3(32, 1, 8), blk, 0, stream>>>(R6, vv_w1, partY,
      BT, 64, 2048, 256, 64);
  reduce_k<<<(BT * 64 + 255) / 256, blk, 0, stream>>>(partY, R0, BT, 64, 64, 8, 0);
  wt_k<<<dim3(2, 64), blk, 0, stream>>>(vv_w2, R1, 64, 2048);
  mgemm_k<EPI_VMIX><<<gM, blk, 0, stream>>>(R0, R1, nullptr, R2,
      BT, 2048, 64, vv_b, R2, v0);

  // ---- k path
  mix_k<<<gridMix, blk, 0, stream>>>(x, xx_k, R6);
  wt_k<<<dim3(64, 64), blk, 0, stream>>>(W_k, R3, 2048, 2048);
  mgemm_k<EPI_BF><<<gM, blk, 0, stream>>>(R6, R3, nullptr, R1,
      BT, 2048, 2048, nullptr, nullptr, nullptr);

  // ---- r path
  mix_k<<<gridMix, blk, 0, stream>>>(x, xx_r, R6);
  wt_k<<<dim3(64, 64), blk, 0, stream>>>(W_r, R3, 2048, 2048);
  mgemm_k<EPI_BF><<<gM, blk, 0, stream>>>(R6, R3, nullptr, R0,
      BT, 2048, 2048, nullptr, nullptr, nullptr);

  // ---- recurrence prep: k(R1),a(R4),r(R0),w_raw(R5) ->
  //      ao(R3), bo(R4), kf(R1), wd(R5), rw(R6), scal
  prep_k<<<BT * HH / 4, blk, 0, stream>>>(R1, R4, R0, R5, kk_s, ka_s,
                                          R3, R4, R1, R5, R6, scal);

  // ---- recurrence (g=16): rw=R6 wd=R5 k=R1 v=R2 ao=R3 bo=R4 -> y
  rec_k<<<256, blk, 0, stream>>>(R6, R5, R1, R2, R3, R4, scal, ws_y);

  // ---- g path (R5, R3, R4, R6 dead after rec)
  mix_k<<<gridMix, blk, 0, stream>>>(x, xx_g, R6);
  gemm_part_k<<<dim3(32, 4, 2), blk, 0, stream>>>(R6, gg_w1, partG,
      BT, 256, 2048, 1024, 256);
  reduce_k<<<(BT * 256 + 255) / 256, blk, 0, stream>>>(partG, R3, BT, 256, 256, 2, 2);
  wt_k<<<dim3(8, 64), blk, 0, stream>>>(gg_w2, R5, 256, 2048);
  mgemm_k<EPI_BF><<<gM, blk, 0, stream>>>(R3, R5, nullptr, R4,
      BT, 2048, 256, nullptr, nullptr, nullptr);

  // ---- groupnorm + bonus + gate (in place on y)
  gn_k<<<BT * HH / 4, blk, 0, stream>>>(ws_y, R0, R1, R2, R4,
                                        rk_s, gn_w, gn_b);

  // ---- final projection y @ W_o -> fp32 output 0
  wt_k<<<dim3(64, 64), blk, 0, stream>>>(W_o, R5, 2048, 2048);
  mgemm_k<EPI_F32><<<gM, blk, 0, stream>>>(ws_y, R5, outF, nullptr,
      BT, 2048, 2048, nullptr, nullptr, nullptr);

  // ---- v0 passthrough (overwrites y scratch + scal, last)
  copy_v0<<<grid4f, blk, 0, stream>>>(v0, outF + NBTC);
}